// Round 2
// baseline (37372.424 us; speedup 1.0000x reference)
//
#include <hip/hip_runtime.h>
#include <math.h>

#define Vc 50257
#define NEG_INF (-__builtin_inff())
#define CHUNK 1024  // vocab columns per vocab block
#define NVB 50      // vocab blocks: 50*1024 >= 50257
#define NB  8       // batch blocks: one per batch

// ---------------- wave-level helpers ----------------

__device__ __forceinline__ float wsum64(float v) {
#pragma unroll
  for (int m = 32; m >= 1; m >>= 1) v += __shfl_xor(v, m, 64);
  return v;
}

__device__ __forceinline__ float red8(float v) {
  v += __shfl_xor(v, 1, 64);
  v += __shfl_xor(v, 2, 64);
  v += __shfl_xor(v, 4, 64);
  return v;
}

// out[lane] = bias[lane] + sum_e x[e]*W[e*64+lane]; x broadcast via LDS float4 reads
__device__ __forceinline__ float proj_lds(float xv, float* xb,
                                          const float* __restrict__ W,
                                          const float* __restrict__ bias, int lane) {
  xb[lane] = xv;
  asm volatile("s_waitcnt lgkmcnt(0)" ::: "memory");
  float acc = bias[lane];
  const float4* x4 = (const float4*)xb;
#pragma unroll
  for (int i = 0; i < 16; ++i) {
    float4 xc = x4[i];
    acc = fmaf(xc.x, W[(4 * i + 0) * 64 + lane], acc);
    acc = fmaf(xc.y, W[(4 * i + 1) * 64 + lane], acc);
    acc = fmaf(xc.z, W[(4 * i + 2) * 64 + lane], acc);
    acc = fmaf(xc.w, W[(4 * i + 3) * 64 + lane], acc);
  }
  asm volatile("" ::: "memory");
  return acc;
}

__device__ __forceinline__ float ln64(float xv, const float* __restrict__ g,
                                      const float* __restrict__ b, int lane) {
  float mean = wsum64(xv) * 0.015625f;
  float d = xv - mean;
  float var = wsum64(d * d) * 0.015625f;
  float r = 1.0f / sqrtf(var + 1e-5f);
  return d * r * g[lane] + b[lane];
}

// ------------- coherent cross-block access: relaxed agent atomics -------------

__device__ __forceinline__ float cloadf(const float* p) {
  return __hip_atomic_load(p, __ATOMIC_RELAXED, __HIP_MEMORY_SCOPE_AGENT);
}
__device__ __forceinline__ int cloadi(const int* p) {
  return __hip_atomic_load(p, __ATOMIC_RELAXED, __HIP_MEMORY_SCOPE_AGENT);
}
__device__ __forceinline__ void cstoref(float* p, float v) {
  __hip_atomic_store(p, v, __ATOMIC_RELAXED, __HIP_MEMORY_SCOPE_AGENT);
}
__device__ __forceinline__ void cstorei(int* p, int v) {
  __hip_atomic_store(p, v, __ATOMIC_RELAXED, __HIP_MEMORY_SCOPE_AGENT);
}
// Bounded spin: ~400x the worst observed wait. If the bound trips, we proceed
// (results go wrong, bench reports absmax failure) instead of hanging the GPU.
__device__ __forceinline__ void spin_until(int* f, int target) {
  int guard = 300000;
  while (__hip_atomic_load(f, __ATOMIC_RELAXED, __HIP_MEMORY_SCOPE_AGENT) < target) {
    __builtin_amdgcn_s_sleep(4);
    if (--guard == 0) break;
  }
  __builtin_amdgcn_s_waitcnt(0);
}
__device__ __forceinline__ void postflag(int* f, int lane) {
  __builtin_amdgcn_s_waitcnt(0);
  if (lane == 0) __hip_atomic_fetch_add(f, 1, __ATOMIC_RELAXED, __HIP_MEMORY_SCOPE_AGENT);
}

struct LayerR {
  const float *saW3, *sab3, *caW0, *cab0, *caW3, *cab3,
              *ffW1, *ffb1, *ffW2, *ffb2, *g0, *be0, *g1, *be1, *g2, *be2;
  float cs1_r, cs2_r, cab1_r, cab2_r;
};

// One wave, one row. K/V in LDS; wv in LDS (float4 broadcast); xb = this wave's LDS scratch.
__device__ float transformer_row(int lane, int t, float x, float q,
                                 const float* Kb, const float* Vb,
                                 const float* wv, float* xb, const LayerR& P) {
  const float ISQ8 = 0.35355339059327373f;  // 1/sqrt(8)
  float mh = NEG_INF;
  for (int k = 0; k < t; ++k) {
    float s = red8(q * Kb[k * 64 + lane]) * ISQ8;
    mh = fmaxf(mh, s);
  }
  float l = 0.f, o = 0.f;
  for (int k = 0; k < t; ++k) {
    float s = red8(q * Kb[k * 64 + lane]) * ISQ8;
    float pw = expf(s - mh);
    l += pw;
    o = fmaf(pw, Vb[k * 64 + lane], o);
  }
  float attn = o / l;
  float y1 = ln64(x + proj_lds(attn, xb, P.saW3, P.sab3, lane), P.g0, P.be0, lane);
  float qc = proj_lds(y1, xb, P.caW0, P.cab0, lane);
  float pa = red8(qc * P.cs1_r);
  float pc = red8(qc * P.cab1_r);
  const float4* wv4 = (const float4*)wv;
  float mc = NEG_INF;
#pragma unroll
  for (int i = 0; i < 16; ++i) {
    float4 wq = wv4[i];
    int k = 4 * i;
    if (k + 0 < t) mc = fmaxf(mc, fmaf(pa, wq.x, pc));
    if (k + 1 < t) mc = fmaxf(mc, fmaf(pa, wq.y, pc));
    if (k + 2 < t) mc = fmaxf(mc, fmaf(pa, wq.z, pc));
    if (k + 3 < t) mc = fmaxf(mc, fmaf(pa, wq.w, pc));
  }
  float lc = 0.f, z = 0.f;
#pragma unroll
  for (int i = 0; i < 16; ++i) {
    float4 wq = wv4[i];
    int k = 4 * i;
    float wk[4] = {wq.x, wq.y, wq.z, wq.w};
#pragma unroll
    for (int j = 0; j < 4; ++j) {
      if (k + j < t) {
        float raw = fmaf(pa, wk[j], pc);
        float pw = expf((raw - mc) * ISQ8);
        lc += pw;
        z = fmaf(pw, wk[j], z);
      }
    }
  }
  float oc = fmaf(z / lc, P.cs2_r, P.cab2_r);
  float y2 = ln64(y1 + proj_lds(oc, xb, P.caW3, P.cab3, lane), P.g1, P.be1, lane);
  float f = fmaxf(proj_lds(y2, xb, P.ffW1, P.ffb1, lane), 0.f);
  float y3 = ln64(y2 + proj_lds(f, xb, P.ffW2, P.ffb2, lane), P.g2, P.be2, lane);
  return y3;
}

__device__ __forceinline__ void build_layer(LayerR& L, int n, int lane,
    const float* sa_W, const float* sa_b, const float* ca_W, const float* ca_b,
    const float* ff_W1, const float* ff_b1, const float* ff_W2, const float* ff_b2,
    const float* ln_g, const float* ln_b) {
  L.saW3 = sa_W + (n * 4 + 3) * 4096; L.sab3 = sa_b + (n * 4 + 3) * 64;
  L.caW0 = ca_W + (n * 4 + 0) * 4096; L.cab0 = ca_b + (n * 4 + 0) * 64;
  L.caW3 = ca_W + (n * 4 + 3) * 4096; L.cab3 = ca_b + (n * 4 + 3) * 64;
  L.ffW1 = ff_W1 + n * 4096;          L.ffb1 = ff_b1 + n * 64;
  L.ffW2 = ff_W2 + n * 4096;          L.ffb2 = ff_b2 + n * 64;
  L.g0 = ln_g + (n * 3 + 0) * 64;     L.be0 = ln_b + (n * 3 + 0) * 64;
  L.g1 = ln_g + (n * 3 + 1) * 64;     L.be1 = ln_b + (n * 3 + 1) * 64;
  L.g2 = ln_g + (n * 3 + 2) * 64;     L.be2 = ln_b + (n * 3 + 2) * 64;
  L.cab1_r = ca_b[(n * 4 + 1) * 64 + lane];
  L.cab2_r = ca_b[(n * 4 + 2) * 64 + lane];
  float c1 = 0.f, c2 = 0.f;
  for (int e = 0; e < 64; ++e) {
    c1 += ca_W[(n * 4 + 1) * 4096 + e * 64 + lane];
    c2 += ca_W[(n * 4 + 2) * 4096 + e * 64 + lane];
  }
  L.cs1_r = c1; L.cs2_r = c2;
}

__global__ __launch_bounds__(1024) void gen_kernel(
    const float* __restrict__ noise, const float* __restrict__ lin_W,
    const float* __restrict__ lin_b, const float* __restrict__ sa_W,
    const float* __restrict__ sa_b, const float* __restrict__ ca_W,
    const float* __restrict__ ca_b, const float* __restrict__ ff_W1,
    const float* __restrict__ ff_b1, const float* __restrict__ ff_W2,
    const float* __restrict__ ff_b2, const float* __restrict__ ln_g,
    const float* __restrict__ ln_b, const float* __restrict__ emb,
    const float* __restrict__ soft_W, const float* __restrict__ soft_b,
    const int* __restrict__ start_id, float* __restrict__ dout,
    float* __restrict__ wsf) {
  const int tid = threadIdx.x, lane = tid & 63, wvid = tid >> 6;
  const int bid = blockIdx.x;

  // ---- workspace: flags in first 8 KB (memset-zeroed), data after ----
  int* wsi = (int*)wsf;
  int* Ff  = wsi;          // [64] tok_feat ready, target NB
  int* C3f = wsi + 64;     // [64] vocab-stats counter, last poster (==NVB-1) reduces
  int* Rf  = wsi + 128;    // [64] m/S/argmax ready, target 1
  float* tokf_g  = wsf + 2048;          // (8,64)
  float* stats_m = wsf + 2560;          // (8,64) use NVB
  float* stats_s = wsf + 3072;
  int*   stats_i = (int*)(wsf + 3584);
  float* mS_g    = wsf + 4096;          // (8,2)
  int*   ig_g    = (int*)(wsf + 4160);  // (8)

  __shared__ float lds[17344];          // 69376 B

  if (bid < NB) {
    // =================== batch block: entire transformer for one batch ===================
    const int b = bid;
    float* K1  = lds;                   // (63,64)
    float* V1  = lds + 4032;
    float* K2  = lds + 8064;
    float* V2  = lds + 12096;
    float* wvl = lds + 16128;           // (64)
    float* x2s = lds + 16192;           // (64) layer-1 out of row t-1
    int*   igl = (int*)(lds + 16256);   // argmax broadcast
    float* xbuf = lds + 16320;          // 16 waves * 64
    float* myxb = xbuf + wvid * 64;

    LayerR L0, L1;
    build_layer(L0, 0, lane, sa_W, sa_b, ca_W, ca_b, ff_W1, ff_b1, ff_W2, ff_b2, ln_g, ln_b);
    build_layer(L1, 1, lane, sa_W, sa_b, ca_W, ca_b, ff_W1, ff_b1, ff_W2, ff_b2, ln_g, ln_b);

    // row r owned by wave (r & 15), register slot (r >> 4); static indexing only
    float x_r[4], q_r[4];
    x_r[0] = x_r[1] = x_r[2] = x_r[3] = 0.f;
    q_r[0] = q_r[1] = q_r[2] = q_r[3] = 0.f;

    if (wvid == 0) {
      float nz = noise[b * 64 + lane];
      float t1v = proj_lds(nz, myxb, lin_W, lin_b, lane);
      float wv_r = proj_lds(t1v, myxb, lin_W + 4096, lin_b + 64, lane);
      wvl[lane] = wv_r;
      // seed row 0 (pe[0]: sin->0, cos->1)
      float y0 = emb[start_id[0] * 64 + lane] + ((lane & 1) ? 1.0f : 0.0f);
      float q0 = proj_lds(y0, myxb, sa_W, sa_b, lane);
      float k0 = proj_lds(y0, myxb, sa_W + 4096, sa_b + 64, lane);
      float v0 = proj_lds(y0, myxb, sa_W + 2 * 4096, sa_b + 128, lane);
      x_r[0] = y0; q_r[0] = q0;
      K1[lane] = k0; V1[lane] = v0;
    }
    __syncthreads();

    for (int t = 1; t <= 63; ++t) {
      // ---- layer-1 for owned rows < t; K2/V2 written straight to LDS ----
#pragma unroll
      for (int j = 0; j < 4; ++j) {
        int w = wvid + 16 * j;
        if (w < t) {
          float out = transformer_row(lane, t, x_r[j], q_r[j], K1, V1, wvl, myxb, L0);
          float k2 = proj_lds(out, myxb, sa_W + 5 * 4096, sa_b + 5 * 64, lane);
          float v2 = proj_lds(out, myxb, sa_W + 6 * 4096, sa_b + 6 * 64, lane);
          K2[w * 64 + lane] = k2;
          V2[w * 64 + lane] = v2;
          if (w == t - 1) x2s[lane] = out;
        }
      }
      __syncthreads();
      // ---- layer-2 for row t-1 (wave 0) ----
      if (wvid == 0) {
        float x2 = x2s[lane];
        float q2 = proj_lds(x2, myxb, sa_W + 4 * 4096, sa_b + 4 * 64, lane);
        float tf = transformer_row(lane, t, x2, q2, K2, V2, wvl, myxb, L1);
        cstoref(tokf_g + b * 64 + lane, tf);
        postflag(&Ff[t], lane);
      }
      // pe row t computed by next row's owner, overlapped with vocab phase
      const int ow = t & 15;
      float pev = 0.f;
      if (t < 63 && wvid == ow) {
        double ang = (double)t / pow(10000.0, (double)(lane & 62) / 64.0);
        pev = (lane & 1) ? (float)cos(ang) : (float)sin(ang);
      }
      if (t < 63) {
        if (tid == 0) {
          spin_until(&Rf[t], 1);
          igl[0] = cloadi(&ig_g[b]);
        }
        __syncthreads();
        if (wvid == ow) {
          float y = emb[igl[0] * 64 + lane] + pev;
          float qn = proj_lds(y, myxb, sa_W, sa_b, lane);
          float kn = proj_lds(y, myxb, sa_W + 4096, sa_b + 64, lane);
          float vn = proj_lds(y, myxb, sa_W + 2 * 4096, sa_b + 128, lane);
          const int slot = t >> 4;  // static-index the register state (no scratch)
          if (slot == 0)      { x_r[0] = y; q_r[0] = qn; }
          else if (slot == 1) { x_r[1] = y; q_r[1] = qn; }
          else if (slot == 2) { x_r[2] = y; q_r[2] = qn; }
          else                { x_r[3] = y; q_r[3] = qn; }
          K1[t * 64 + lane] = kn;
          V1[t * 64 + lane] = vn;
        }
        __syncthreads();
      }
    }
  } else {
    // =================== vocab block: fixed 1024-column slice ===================
    const int jb = bid - NB;
    const int v = jb * CHUNK + tid;
    const bool valid = v < Vc;
    float* ftile = lds;                 // (512)
    float* sm  = lds + 512;             // (16,8)
    int*   si  = (int*)(lds + 640);
    float* ssm = lds + 768;             // (16,8)
    float* bmx = lds + 896;             // (8)
    int*   bix = (int*)(lds + 904);
    float* msl = lds + 920;             // (16)
    int*   red = (int*)(lds + 936);
    float sb = valid ? soft_b[v] : 0.f;

    for (int t = 1; t <= 63; ++t) {
      if (tid == 0) spin_until(&Ff[t], NB);
      __syncthreads();
      if (tid < 512) ftile[tid] = cloadf(&tokf_g[tid]);
      __syncthreads();
      float lg[8];
#pragma unroll
      for (int b = 0; b < 8; ++b) lg[b] = valid ? sb : NEG_INF;
      if (valid) {
        for (int e = 0; e < 64; ++e) {
          float wc = soft_W[e * Vc + v];
#pragma unroll
          for (int b = 0; b < 8; ++b) lg[b] = fmaf(ftile[b * 64 + e], wc, lg[b]);
        }
      }
#pragma unroll
      for (int b = 0; b < 8; ++b) {
        float m = lg[b]; int ix = valid ? v : 0x7fffffff;
#pragma unroll
        for (int msk = 1; msk < 64; msk <<= 1) {
          float om = __shfl_xor(m, msk, 64);
          int oi = __shfl_xor(ix, msk, 64);
          if (om > m || (om == m && oi < ix)) { m = om; ix = oi; }
        }
        if (lane == 0) { sm[wvid * 8 + b] = m; si[wvid * 8 + b] = ix; }
      }
      __syncthreads();
      if (tid < 8) {
        float m = NEG_INF; int ix = 0x7fffffff;
        for (int wv = 0; wv < 16; ++wv) {
          float om = sm[wv * 8 + tid]; int oi = si[wv * 8 + tid];
          if (om > m || (om == m && oi < ix)) { m = om; ix = oi; }
        }
        bmx[tid] = m; bix[tid] = ix;
      }
      __syncthreads();
#pragma unroll
      for (int b = 0; b < 8; ++b) {
        float c = valid ? expf(lg[b] - bmx[b]) : 0.f;
        float s = wsum64(c);
        if (lane == 0) ssm[wvid * 8 + b] = s;
      }
      __syncthreads();
      if (wvid == 0) {
        if (lane < 8) {
          float s = 0.f;
          for (int wv = 0; wv < 16; ++wv) s += ssm[wv * 8 + lane];
          cstoref(&stats_m[lane * 64 + jb], bmx[lane]);
          cstoref(&stats_s[lane * 64 + jb], s);
          cstorei(&stats_i[lane * 64 + jb], bix[lane]);
        }
        __builtin_amdgcn_s_waitcnt(0);  // stats at coherence point before counting in
        if (lane == 0)
          red[0] = __hip_atomic_fetch_add(&C3f[t], 1, __ATOMIC_RELAXED, __HIP_MEMORY_SCOPE_AGENT);
      }
      __syncthreads();
      if (red[0] == NVB - 1) {
        // last-arriving vocab block reduces all 8 batches (no leader poll latency)
        if (wvid < 8) {
          const int b2 = wvid;
          bool act = lane < NVB;
          float m = act ? cloadf(&stats_m[b2 * 64 + lane]) : NEG_INF;
          float sv = act ? cloadf(&stats_s[b2 * 64 + lane]) : 0.f;
          int ix = act ? cloadi(&stats_i[b2 * 64 + lane]) : 0x7fffffff;
          float mg = m; int ig = ix;
#pragma unroll
          for (int msk = 1; msk < 64; msk <<= 1) {
            float om = __shfl_xor(mg, msk, 64);
            int oi = __shfl_xor(ig, msk, 64);
            if (om > mg || (om == mg && oi < ig)) { mg = om; ig = oi; }
          }
          float S = wsum64(act ? sv * expf(m - mg) : 0.f);
          if (lane == 0) {
            cstoref(&mS_g[b2 * 2], mg);
            cstoref(&mS_g[b2 * 2 + 1], S);
            cstorei(&ig_g[b2], ig);
          }
          __builtin_amdgcn_s_waitcnt(0);  // each reducing wave drains its own stores
        }
        __syncthreads();
        if (tid == 0)
          __hip_atomic_fetch_add(&Rf[t], 1, __ATOMIC_RELAXED, __HIP_MEMORY_SCOPE_AGENT);
      }
      if (tid == 0) spin_until(&Rf[t], 1);
      __syncthreads();
      if (tid < 16) msl[tid] = cloadf(&mS_g[tid]);
      __syncthreads();
      if (valid) {
        long base = (long)(t - 1) * Vc + v;
#pragma unroll
        for (int b = 0; b < 8; ++b)
          dout[(long)b * 63 * Vc + base] = expf(lg[b] - msl[2 * b]) / msl[2 * b + 1];
      }
      __syncthreads();
    }
  }
}

extern "C" void kernel_launch(void* const* d_in, const int* in_sizes, int n_in,
                              void* d_out, int out_size, void* d_ws, size_t ws_size,
                              hipStream_t stream) {
  (void)in_sizes; (void)n_in; (void)out_size; (void)ws_size;
  hipMemsetAsync(d_ws, 0, 8192, stream);  // zero all flag arrays
  gen_kernel<<<dim3(NB + NVB), dim3(1024), 0, stream>>>(
      (const float*)d_in[0], (const float*)d_in[1], (const float*)d_in[2],
      (const float*)d_in[3], (const float*)d_in[4], (const float*)d_in[5],
      (const float*)d_in[6], (const float*)d_in[7], (const float*)d_in[8],
      (const float*)d_in[9], (const float*)d_in[10], (const float*)d_in[11],
      (const float*)d_in[12], (const float*)d_in[13], (const float*)d_in[14],
      (const float*)d_in[15], (const int*)d_in[16],
      (float*)d_out, (float*)d_ws);
}

// Round 3
// 31028.537 us; speedup vs baseline: 1.2045x; 1.2045x over previous
//
#include <hip/hip_runtime.h>
#include <math.h>

#define Vc 50257
#define NEG_INF (-__builtin_inff())
#define VCOLS 397   // vocab columns per vocab block (LDS-resident slice)
#define NVB 127     // 127*397 = 50419 >= 50257
#define NB  8       // batch blocks: one per batch

// ---------------- wave-level helpers ----------------

__device__ __forceinline__ float wsum64(float v) {
#pragma unroll
  for (int m = 32; m >= 1; m >>= 1) v += __shfl_xor(v, m, 64);
  return v;
}

__device__ __forceinline__ float red8(float v) {
  v += __shfl_xor(v, 1, 64);
  v += __shfl_xor(v, 2, 64);
  v += __shfl_xor(v, 4, 64);
  return v;
}

// out[lane] = bias[lane] + sum_e x[e]*W[e*64+lane]; x broadcast via LDS float4 reads
__device__ __forceinline__ float proj_lds(float xv, float* xb,
                                          const float* __restrict__ W,
                                          const float* __restrict__ bias, int lane) {
  xb[lane] = xv;
  asm volatile("s_waitcnt lgkmcnt(0)" ::: "memory");
  float acc = bias[lane];
  const float4* x4 = (const float4*)xb;
#pragma unroll
  for (int i = 0; i < 16; ++i) {
    float4 xc = x4[i];
    acc = fmaf(xc.x, W[(4 * i + 0) * 64 + lane], acc);
    acc = fmaf(xc.y, W[(4 * i + 1) * 64 + lane], acc);
    acc = fmaf(xc.z, W[(4 * i + 2) * 64 + lane], acc);
    acc = fmaf(xc.w, W[(4 * i + 3) * 64 + lane], acc);
  }
  asm volatile("" ::: "memory");
  return acc;
}

__device__ __forceinline__ float ln64(float xv, const float* __restrict__ g,
                                      const float* __restrict__ b, int lane) {
  float mean = wsum64(xv) * 0.015625f;
  float d = xv - mean;
  float var = wsum64(d * d) * 0.015625f;
  float r = 1.0f / sqrtf(var + 1e-5f);
  return d * r * g[lane] + b[lane];
}

// ------------- coherent cross-block access: relaxed agent atomics -------------

__device__ __forceinline__ float cloadf(const float* p) {
  return __hip_atomic_load(p, __ATOMIC_RELAXED, __HIP_MEMORY_SCOPE_AGENT);
}
__device__ __forceinline__ int cloadi(const int* p) {
  return __hip_atomic_load(p, __ATOMIC_RELAXED, __HIP_MEMORY_SCOPE_AGENT);
}
__device__ __forceinline__ void cstoref(float* p, float v) {
  __hip_atomic_store(p, v, __ATOMIC_RELAXED, __HIP_MEMORY_SCOPE_AGENT);
}
__device__ __forceinline__ void cstorei(int* p, int v) {
  __hip_atomic_store(p, v, __ATOMIC_RELAXED, __HIP_MEMORY_SCOPE_AGENT);
}
// Bounded spin: if the bound trips we proceed (bench reports absmax failure)
// instead of hanging the GPU.
__device__ __forceinline__ void spin_until(int* f, int target) {
  int guard = 300000;
  while (__hip_atomic_load(f, __ATOMIC_RELAXED, __HIP_MEMORY_SCOPE_AGENT) < target) {
    __builtin_amdgcn_s_sleep(4);
    if (--guard == 0) break;
  }
  __builtin_amdgcn_s_waitcnt(0);
}
__device__ __forceinline__ void postflag(int* f, int lane) {
  __builtin_amdgcn_s_waitcnt(0);
  if (lane == 0) __hip_atomic_fetch_add(f, 1, __ATOMIC_RELAXED, __HIP_MEMORY_SCOPE_AGENT);
}

struct LayerR {
  const float *saW3, *sab3, *caW0, *cab0, *caW3, *cab3,
              *ffW1, *ffb1, *ffW2, *ffb2, *g0, *be0, *g1, *be1, *g2, *be2;
  float cs1_r, cs2_r, cab1_r, cab2_r;
};

// One wave, one row. K/V in LDS with row stride 65 (bank = (k+e)%32 -> 2-way, free).
// Self-attention: lane=k score phase (8 head dots per lane, per-head summation order
// matches the reference einsum), wave-reduce max/sum (8x6 shfl), normalized P to
// per-wave pbuf, then lane=e PV phase. No per-k serial swizzle chains.
__device__ float transformer_row(int lane, int t, float x, float q,
                                 const float* Kb, const float* Vb,
                                 const float* wv, float* xb, float* pb,
                                 const LayerR& P) {
  const float ISQ8 = 0.35355339059327373f;  // 1/sqrt(8)
  // ---- scores: lane = k ----
  xb[lane] = q;
  asm volatile("s_waitcnt lgkmcnt(0)" ::: "memory");
  float a[8] = {0.f, 0.f, 0.f, 0.f, 0.f, 0.f, 0.f, 0.f};
  const float* Krow = Kb + lane * 65;
  const float4* xq4 = (const float4*)xb;
#pragma unroll
  for (int i = 0; i < 16; ++i) {
    float4 xc = xq4[i];
    a[i >> 1] = fmaf(xc.x, Krow[4 * i + 0], a[i >> 1]);
    a[i >> 1] = fmaf(xc.y, Krow[4 * i + 1], a[i >> 1]);
    a[i >> 1] = fmaf(xc.z, Krow[4 * i + 2], a[i >> 1]);
    a[i >> 1] = fmaf(xc.w, Krow[4 * i + 3], a[i >> 1]);
  }
  const bool act = lane < t;
  float m[8];
#pragma unroll
  for (int h = 0; h < 8; ++h) { a[h] = act ? a[h] * ISQ8 : NEG_INF; m[h] = a[h]; }
#pragma unroll
  for (int msk = 1; msk < 64; msk <<= 1) {
#pragma unroll
    for (int h = 0; h < 8; ++h) m[h] = fmaxf(m[h], __shfl_xor(m[h], msk, 64));
  }
  float l[8];
#pragma unroll
  for (int h = 0; h < 8; ++h) { a[h] = act ? expf(a[h] - m[h]) : 0.f; l[h] = a[h]; }
#pragma unroll
  for (int msk = 1; msk < 64; msk <<= 1) {
#pragma unroll
    for (int h = 0; h < 8; ++h) l[h] += __shfl_xor(l[h], msk, 64);
  }
#pragma unroll
  for (int h = 0; h < 8; ++h) pb[h * 64 + lane] = a[h] / l[h];
  asm volatile("s_waitcnt lgkmcnt(0)" ::: "memory");
  // ---- PV: lane = e ----
  const float* pr = pb + (lane >> 3) * 64;
  float attn = 0.f;
  for (int k = 0; k < t; ++k) attn = fmaf(pr[k], Vb[k * 65 + lane], attn);

  float y1 = ln64(x + proj_lds(attn, xb, P.saW3, P.sab3, lane), P.g0, P.be0, lane);
  float qc = proj_lds(y1, xb, P.caW0, P.cab0, lane);
  float pa = red8(qc * P.cs1_r);
  float pc = red8(qc * P.cab1_r);
  const float4* wv4 = (const float4*)wv;
  float mc = NEG_INF;
#pragma unroll
  for (int i = 0; i < 16; ++i) {
    float4 wq = wv4[i];
    int k = 4 * i;
    if (k + 0 < t) mc = fmaxf(mc, fmaf(pa, wq.x, pc));
    if (k + 1 < t) mc = fmaxf(mc, fmaf(pa, wq.y, pc));
    if (k + 2 < t) mc = fmaxf(mc, fmaf(pa, wq.z, pc));
    if (k + 3 < t) mc = fmaxf(mc, fmaf(pa, wq.w, pc));
  }
  float lc = 0.f, z = 0.f;
#pragma unroll
  for (int i = 0; i < 16; ++i) {
    float4 wq = wv4[i];
    int k = 4 * i;
    float wk[4] = {wq.x, wq.y, wq.z, wq.w};
#pragma unroll
    for (int j = 0; j < 4; ++j) {
      if (k + j < t) {
        float raw = fmaf(pa, wk[j], pc);
        float pw = expf((raw - mc) * ISQ8);
        lc += pw;
        z = fmaf(pw, wk[j], z);
      }
    }
  }
  float oc = fmaf(z / lc, P.cs2_r, P.cab2_r);
  float y2 = ln64(y1 + proj_lds(oc, xb, P.caW3, P.cab3, lane), P.g1, P.be1, lane);
  float f = fmaxf(proj_lds(y2, xb, P.ffW1, P.ffb1, lane), 0.f);
  float y3 = ln64(y2 + proj_lds(f, xb, P.ffW2, P.ffb2, lane), P.g2, P.be2, lane);
  return y3;
}

__device__ __forceinline__ void build_layer(LayerR& L, int n, int lane,
    const float* sa_W, const float* sa_b, const float* ca_W, const float* ca_b,
    const float* ff_W1, const float* ff_b1, const float* ff_W2, const float* ff_b2,
    const float* ln_g, const float* ln_b) {
  L.saW3 = sa_W + (n * 4 + 3) * 4096; L.sab3 = sa_b + (n * 4 + 3) * 64;
  L.caW0 = ca_W + (n * 4 + 0) * 4096; L.cab0 = ca_b + (n * 4 + 0) * 64;
  L.caW3 = ca_W + (n * 4 + 3) * 4096; L.cab3 = ca_b + (n * 4 + 3) * 64;
  L.ffW1 = ff_W1 + n * 4096;          L.ffb1 = ff_b1 + n * 64;
  L.ffW2 = ff_W2 + n * 4096;          L.ffb2 = ff_b2 + n * 64;
  L.g0 = ln_g + (n * 3 + 0) * 64;     L.be0 = ln_b + (n * 3 + 0) * 64;
  L.g1 = ln_g + (n * 3 + 1) * 64;     L.be1 = ln_b + (n * 3 + 1) * 64;
  L.g2 = ln_g + (n * 3 + 2) * 64;     L.be2 = ln_b + (n * 3 + 2) * 64;
  L.cab1_r = ca_b[(n * 4 + 1) * 64 + lane];
  L.cab2_r = ca_b[(n * 4 + 2) * 64 + lane];
  float c1 = 0.f, c2 = 0.f;
  for (int e = 0; e < 64; ++e) {
    c1 += ca_W[(n * 4 + 1) * 4096 + e * 64 + lane];
    c2 += ca_W[(n * 4 + 2) * 4096 + e * 64 + lane];
  }
  L.cs1_r = c1; L.cs2_r = c2;
}

__global__ __launch_bounds__(1024) void gen_kernel(
    const float* __restrict__ noise, const float* __restrict__ lin_W,
    const float* __restrict__ lin_b, const float* __restrict__ sa_W,
    const float* __restrict__ sa_b, const float* __restrict__ ca_W,
    const float* __restrict__ ca_b, const float* __restrict__ ff_W1,
    const float* __restrict__ ff_b1, const float* __restrict__ ff_W2,
    const float* __restrict__ ff_b2, const float* __restrict__ ln_g,
    const float* __restrict__ ln_b, const float* __restrict__ emb,
    const float* __restrict__ soft_W, const float* __restrict__ soft_b,
    const int* __restrict__ start_id, float* __restrict__ dout,
    float* __restrict__ wsf) {
  const int tid = threadIdx.x, lane = tid & 63, wvid = tid >> 6;
  const int bid = blockIdx.x;

  // ---- workspace: flags in first 8 KB (memset-zeroed), data after ----
  int* wsi = (int*)wsf;
  int* Ff  = wsi;          // [64] tok_feat ready, target NB
  int* C3f = wsi + 64;     // [64] vocab-stats counter, last poster (==NVB-1) reduces
  int* Rf  = wsi + 128;    // [64] m/S/argmax ready, target 1
  float* tokf_g  = wsf + 2048;          // (8,64)
  float* stats_m = wsf + 2560;          // (8,128) use NVB
  float* stats_s = wsf + 3584;          // (8,128)
  int*   stats_i = (int*)(wsf + 4608);  // (8,128)
  float* mS_g    = wsf + 5632;          // (8,2)
  int*   ig_g    = (int*)(wsf + 5648);  // (8)

  __shared__ float lds[26368];          // 105472 B

  if (bid < NB) {
    // =================== batch block: entire transformer for one batch ===================
    const int b = bid;
    float* K1  = lds;                   // 63 rows, stride 65
    float* V1  = lds + 4096;
    float* K2  = lds + 8192;
    float* V2  = lds + 12288;
    float* wvl = lds + 16384;           // (64)
    float* x2s = lds + 16448;           // (64) layer-1 out of row t-1
    int*   igl = (int*)(lds + 16512);   // argmax broadcast
    float* xbuf = lds + 16576;          // 16 waves * 64
    float* pbuf = lds + 17600;          // 16 waves * 512 (P buffers, h*64+k)
    float* myxb = xbuf + wvid * 64;
    float* mypb = pbuf + wvid * 512;

    LayerR L0, L1;
    build_layer(L0, 0, lane, sa_W, sa_b, ca_W, ca_b, ff_W1, ff_b1, ff_W2, ff_b2, ln_g, ln_b);
    build_layer(L1, 1, lane, sa_W, sa_b, ca_W, ca_b, ff_W1, ff_b1, ff_W2, ff_b2, ln_g, ln_b);

    // row r owned by wave (r & 15), register slot (r >> 4); static indexing only
    float x_r[4], q_r[4];
    x_r[0] = x_r[1] = x_r[2] = x_r[3] = 0.f;
    q_r[0] = q_r[1] = q_r[2] = q_r[3] = 0.f;

    if (wvid == 0) {
      float nz = noise[b * 64 + lane];
      float t1v = proj_lds(nz, myxb, lin_W, lin_b, lane);
      float wv_r = proj_lds(t1v, myxb, lin_W + 4096, lin_b + 64, lane);
      wvl[lane] = wv_r;
      // seed row 0 (pe[0]: sin->0, cos->1)
      float y0 = emb[start_id[0] * 64 + lane] + ((lane & 1) ? 1.0f : 0.0f);
      float q0 = proj_lds(y0, myxb, sa_W, sa_b, lane);
      float k0 = proj_lds(y0, myxb, sa_W + 4096, sa_b + 64, lane);
      float v0 = proj_lds(y0, myxb, sa_W + 2 * 4096, sa_b + 128, lane);
      x_r[0] = y0; q_r[0] = q0;
      K1[lane] = k0; V1[lane] = v0;
    }
    __syncthreads();

    for (int t = 1; t <= 63; ++t) {
      // ---- layer-1 for owned rows < t; K2/V2 written straight to LDS ----
#pragma unroll
      for (int j = 0; j < 4; ++j) {
        int w = wvid + 16 * j;
        if (w < t) {
          float out = transformer_row(lane, t, x_r[j], q_r[j], K1, V1, wvl, myxb, mypb, L0);
          float k2 = proj_lds(out, myxb, sa_W + 5 * 4096, sa_b + 5 * 64, lane);
          float v2 = proj_lds(out, myxb, sa_W + 6 * 4096, sa_b + 6 * 64, lane);
          K2[w * 65 + lane] = k2;
          V2[w * 65 + lane] = v2;
          if (w == t - 1) x2s[lane] = out;
        }
      }
      __syncthreads();
      // ---- layer-2 for row t-1 (wave 0) ----
      if (wvid == 0) {
        float x2 = x2s[lane];
        float q2 = proj_lds(x2, myxb, sa_W + 4 * 4096, sa_b + 4 * 64, lane);
        float tf = transformer_row(lane, t, x2, q2, K2, V2, wvl, myxb, mypb, L1);
        cstoref(tokf_g + b * 64 + lane, tf);
        postflag(&Ff[t], lane);
      }
      // pe row t computed by next row's owner, overlapped with vocab phase
      const int ow = t & 15;
      float pev = 0.f;
      if (t < 63 && wvid == ow) {
        double ang = (double)t / pow(10000.0, (double)(lane & 62) / 64.0);
        pev = (lane & 1) ? (float)cos(ang) : (float)sin(ang);
      }
      if (t < 63) {
        if (tid == 0) {
          spin_until(&Rf[t], 1);
          igl[0] = cloadi(&ig_g[b]);
        }
        __syncthreads();
        if (wvid == ow) {
          float y = emb[igl[0] * 64 + lane] + pev;
          float qn = proj_lds(y, myxb, sa_W, sa_b, lane);
          float kn = proj_lds(y, myxb, sa_W + 4096, sa_b + 64, lane);
          float vn = proj_lds(y, myxb, sa_W + 2 * 4096, sa_b + 128, lane);
          const int slot = t >> 4;  // static-index the register state (no scratch)
          if (slot == 0)      { x_r[0] = y; q_r[0] = qn; }
          else if (slot == 1) { x_r[1] = y; q_r[1] = qn; }
          else if (slot == 2) { x_r[2] = y; q_r[2] = qn; }
          else                { x_r[3] = y; q_r[3] = qn; }
          K1[t * 65 + lane] = kn;
          V1[t * 65 + lane] = vn;
        }
        __syncthreads();
      }
    }
  } else {
    // =================== vocab block: LDS-resident 397-column slice ===================
    const int jb = bid - NB;
    const int v = jb * VCOLS + tid;
    const bool valid = (tid < VCOLS) && (v < Vc);
    float* sW  = lds;                   // (64, 397) LDS-resident soft_W slice
    float* f2  = lds + 25408;           // (64,8) ftile transposed, e*8+b
    float* sm  = lds + 25920;           // (16,8)
    int*   si  = (int*)(lds + 26048);
    float* ssm = lds + 26176;           // (16,8)
    float* bmx = lds + 26304;           // (8)
    int*   bix = (int*)(lds + 26312);
    float* msl = lds + 26320;           // (16)
    int*   red = (int*)(lds + 26336);
    float sb = valid ? soft_b[v] : 0.f;

    // one-time stage of this block's soft_W slice into LDS (~102 KB)
    if (tid < VCOLS) {
      for (int e = 0; e < 64; ++e)
        sW[e * VCOLS + tid] = (v < Vc) ? soft_W[e * Vc + v] : 0.f;
    }
    __syncthreads();

    for (int t = 1; t <= 63; ++t) {
      if (tid == 0) spin_until(&Ff[t], NB);
      __syncthreads();
      if (tid < 512) f2[tid] = cloadf(&tokf_g[(tid & 7) * 64 + (tid >> 3)]);
      __syncthreads();
      float lg[8];
#pragma unroll
      for (int b = 0; b < 8; ++b) lg[b] = valid ? sb : NEG_INF;
      if (valid) {
        const float4* f4 = (const float4*)f2;
        const float* col = sW + tid;
#pragma unroll 8
        for (int e = 0; e < 64; ++e) {
          float wc = col[e * VCOLS];
          float4 fa = f4[2 * e], fb = f4[2 * e + 1];
          lg[0] = fmaf(fa.x, wc, lg[0]);
          lg[1] = fmaf(fa.y, wc, lg[1]);
          lg[2] = fmaf(fa.z, wc, lg[2]);
          lg[3] = fmaf(fa.w, wc, lg[3]);
          lg[4] = fmaf(fb.x, wc, lg[4]);
          lg[5] = fmaf(fb.y, wc, lg[5]);
          lg[6] = fmaf(fb.z, wc, lg[6]);
          lg[7] = fmaf(fb.w, wc, lg[7]);
        }
      }
#pragma unroll
      for (int b = 0; b < 8; ++b) {
        float m = lg[b]; int ix = valid ? v : 0x7fffffff;
#pragma unroll
        for (int msk = 1; msk < 64; msk <<= 1) {
          float om = __shfl_xor(m, msk, 64);
          int oi = __shfl_xor(ix, msk, 64);
          if (om > m || (om == m && oi < ix)) { m = om; ix = oi; }
        }
        if (lane == 0) { sm[wvid * 8 + b] = m; si[wvid * 8 + b] = ix; }
      }
      __syncthreads();
      if (tid < 8) {
        float m = NEG_INF; int ix = 0x7fffffff;
        for (int wv = 0; wv < 16; ++wv) {
          float om = sm[wv * 8 + tid]; int oi = si[wv * 8 + tid];
          if (om > m || (om == m && oi < ix)) { m = om; ix = oi; }
        }
        bmx[tid] = m; bix[tid] = ix;
      }
      __syncthreads();
#pragma unroll
      for (int b = 0; b < 8; ++b) {
        float c = valid ? expf(lg[b] - bmx[b]) : 0.f;
        float s = wsum64(c);
        if (lane == 0) ssm[wvid * 8 + b] = s;
      }
      __syncthreads();
      if (wvid == 0) {
        if (lane < 8) {
          float s = 0.f;
          for (int wv = 0; wv < 16; ++wv) s += ssm[wv * 8 + lane];
          cstoref(&stats_m[lane * 128 + jb], bmx[lane]);
          cstoref(&stats_s[lane * 128 + jb], s);
          cstorei(&stats_i[lane * 128 + jb], bix[lane]);
        }
        __builtin_amdgcn_s_waitcnt(0);  // stats at coherence point before counting in
        if (lane == 0)
          red[0] = __hip_atomic_fetch_add(&C3f[t], 1, __ATOMIC_RELAXED, __HIP_MEMORY_SCOPE_AGENT);
      }
      __syncthreads();
      if (red[0] == NVB - 1) {
        // last-arriving vocab block reduces all 8 batches (no leader poll latency)
        if (wvid < 8) {
          const int b2 = wvid;
          float mA = cloadf(&stats_m[b2 * 128 + lane]);
          float sA = cloadf(&stats_s[b2 * 128 + lane]);
          int   iA = cloadi(&stats_i[b2 * 128 + lane]);
          const bool a2 = lane < (NVB - 64);
          float mB = a2 ? cloadf(&stats_m[b2 * 128 + 64 + lane]) : NEG_INF;
          float sB = a2 ? cloadf(&stats_s[b2 * 128 + 64 + lane]) : 0.f;
          int   iB = a2 ? cloadi(&stats_i[b2 * 128 + 64 + lane]) : 0x7fffffff;
          float mg = mA; int ig = iA;
          if (mB > mg || (mB == mg && iB < ig)) { mg = mB; ig = iB; }
#pragma unroll
          for (int msk = 1; msk < 64; msk <<= 1) {
            float om = __shfl_xor(mg, msk, 64);
            int oi = __shfl_xor(ig, msk, 64);
            if (om > mg || (om == mg && oi < ig)) { mg = om; ig = oi; }
          }
          float part = sA * expf(mA - mg) + (a2 ? sB * expf(mB - mg) : 0.f);
          float S = wsum64(part);
          if (lane == 0) {
            cstoref(&mS_g[b2 * 2], mg);
            cstoref(&mS_g[b2 * 2 + 1], S);
            cstorei(&ig_g[b2], ig);
          }
          __builtin_amdgcn_s_waitcnt(0);  // each reducing wave drains its own stores
        }
        __syncthreads();
        if (tid == 0)
          __hip_atomic_fetch_add(&Rf[t], 1, __ATOMIC_RELAXED, __HIP_MEMORY_SCOPE_AGENT);
      }
      if (tid == 0) spin_until(&Rf[t], 1);
      __syncthreads();
      if (tid < 16) msl[tid] = cloadf(&mS_g[tid]);
      __syncthreads();
      if (valid) {
        long base = (long)(t - 1) * Vc + v;
#pragma unroll
        for (int b = 0; b < 8; ++b)
          dout[(long)b * 63 * Vc + base] = expf(lg[b] - msl[2 * b]) / msl[2 * b + 1];
      }
      __syncthreads();
    }
  }
}

extern "C" void kernel_launch(void* const* d_in, const int* in_sizes, int n_in,
                              void* d_out, int out_size, void* d_ws, size_t ws_size,
                              hipStream_t stream) {
  (void)in_sizes; (void)n_in; (void)out_size; (void)ws_size;
  hipMemsetAsync(d_ws, 0, 8192, stream);  // zero all flag arrays
  gen_kernel<<<dim3(NB + NVB), dim3(1024), 0, stream>>>(
      (const float*)d_in[0], (const float*)d_in[1], (const float*)d_in[2],
      (const float*)d_in[3], (const float*)d_in[4], (const float*)d_in[5],
      (const float*)d_in[6], (const float*)d_in[7], (const float*)d_in[8],
      (const float*)d_in[9], (const float*)d_in[10], (const float*)d_in[11],
      (const float*)d_in[12], (const float*)d_in[13], (const float*)d_in[14],
      (const float*)d_in[15], (const int*)d_in[16],
      (float*)d_out, (float*)d_ws);
}

// Round 4
// 23992.906 us; speedup vs baseline: 1.5576x; 1.2932x over previous
//
#include <hip/hip_runtime.h>
#include <math.h>

#define Vc 50257
#define NEG_INF (-__builtin_inff())
#define VCOLS 397   // vocab columns per vocab block (LDS-resident slice)
#define NVB 127     // 127*397 = 50419 >= 50257
#define NB  8       // batches
#define NBB 32      // batch blocks: 4 per batch, 16 rows each, 1 row per wave

// ---------------- wave-level helpers ----------------

__device__ __forceinline__ float wsum64(float v) {
#pragma unroll
  for (int m = 32; m >= 1; m >>= 1) v += __shfl_xor(v, m, 64);
  return v;
}

__device__ __forceinline__ float red8(float v) {
  v += __shfl_xor(v, 1, 64);
  v += __shfl_xor(v, 2, 64);
  v += __shfl_xor(v, 4, 64);
  return v;
}

// out[lane] = bias[lane] + sum_e x[e]*W[e*64+lane]; x broadcast via LDS float4 reads
__device__ __forceinline__ float proj_lds(float xv, float* xb,
                                          const float* __restrict__ W,
                                          const float* __restrict__ bias, int lane) {
  xb[lane] = xv;
  asm volatile("s_waitcnt lgkmcnt(0)" ::: "memory");
  float acc = bias[lane];
  const float4* x4 = (const float4*)xb;
#pragma unroll
  for (int i = 0; i < 16; ++i) {
    float4 xc = x4[i];
    acc = fmaf(xc.x, W[(4 * i + 0) * 64 + lane], acc);
    acc = fmaf(xc.y, W[(4 * i + 1) * 64 + lane], acc);
    acc = fmaf(xc.z, W[(4 * i + 2) * 64 + lane], acc);
    acc = fmaf(xc.w, W[(4 * i + 3) * 64 + lane], acc);
  }
  asm volatile("" ::: "memory");
  return acc;
}

__device__ __forceinline__ float ln64(float xv, const float* __restrict__ g,
                                      const float* __restrict__ b, int lane) {
  float mean = wsum64(xv) * 0.015625f;
  float d = xv - mean;
  float var = wsum64(d * d) * 0.015625f;
  float r = 1.0f / sqrtf(var + 1e-5f);
  return d * r * g[lane] + b[lane];
}

// ------------- coherent cross-block access: relaxed agent atomics -------------

__device__ __forceinline__ float cloadf(const float* p) {
  return __hip_atomic_load(p, __ATOMIC_RELAXED, __HIP_MEMORY_SCOPE_AGENT);
}
__device__ __forceinline__ int cloadi(const int* p) {
  return __hip_atomic_load(p, __ATOMIC_RELAXED, __HIP_MEMORY_SCOPE_AGENT);
}
__device__ __forceinline__ void cstoref(float* p, float v) {
  __hip_atomic_store(p, v, __ATOMIC_RELAXED, __HIP_MEMORY_SCOPE_AGENT);
}
__device__ __forceinline__ void cstorei(int* p, int v) {
  __hip_atomic_store(p, v, __ATOMIC_RELAXED, __HIP_MEMORY_SCOPE_AGENT);
}
// Bounded spin: if the bound trips we proceed (bench reports absmax failure)
// instead of hanging the GPU.
__device__ __forceinline__ void spin_until(int* f, int target) {
  int guard = 300000;
  while (__hip_atomic_load(f, __ATOMIC_RELAXED, __HIP_MEMORY_SCOPE_AGENT) < target) {
    __builtin_amdgcn_s_sleep(4);
    if (--guard == 0) break;
  }
  __builtin_amdgcn_s_waitcnt(0);
}
__device__ __forceinline__ void postflag(int* f, int lane) {
  __builtin_amdgcn_s_waitcnt(0);
  if (lane == 0) __hip_atomic_fetch_add(f, 1, __ATOMIC_RELAXED, __HIP_MEMORY_SCOPE_AGENT);
}

struct LayerR {
  const float *saW3, *sab3, *caW0, *cab0, *caW3, *cab3,
              *ffW1, *ffb1, *ffW2, *ffb2, *g0, *be0, *g1, *be1, *g2, *be2;
  float cs1_r, cs2_r, cab1_r, cab2_r;
};

// One wave, one row. K/V in LDS with row stride 65 (bank = (k+e)%32 -> 2-way, free).
__device__ float transformer_row(int lane, int t, float x, float q,
                                 const float* Kb, const float* Vb,
                                 const float* wv, float* xb, float* pb,
                                 const LayerR& P) {
  const float ISQ8 = 0.35355339059327373f;  // 1/sqrt(8)
  // ---- scores: lane = k ----
  xb[lane] = q;
  asm volatile("s_waitcnt lgkmcnt(0)" ::: "memory");
  float a[8] = {0.f, 0.f, 0.f, 0.f, 0.f, 0.f, 0.f, 0.f};
  const float* Krow = Kb + lane * 65;
  const float4* xq4 = (const float4*)xb;
#pragma unroll
  for (int i = 0; i < 16; ++i) {
    float4 xc = xq4[i];
    a[i >> 1] = fmaf(xc.x, Krow[4 * i + 0], a[i >> 1]);
    a[i >> 1] = fmaf(xc.y, Krow[4 * i + 1], a[i >> 1]);
    a[i >> 1] = fmaf(xc.z, Krow[4 * i + 2], a[i >> 1]);
    a[i >> 1] = fmaf(xc.w, Krow[4 * i + 3], a[i >> 1]);
  }
  const bool act = lane < t;
  float m[8];
#pragma unroll
  for (int h = 0; h < 8; ++h) { a[h] = act ? a[h] * ISQ8 : NEG_INF; m[h] = a[h]; }
#pragma unroll
  for (int msk = 1; msk < 64; msk <<= 1) {
#pragma unroll
    for (int h = 0; h < 8; ++h) m[h] = fmaxf(m[h], __shfl_xor(m[h], msk, 64));
  }
  float l[8];
#pragma unroll
  for (int h = 0; h < 8; ++h) { a[h] = act ? expf(a[h] - m[h]) : 0.f; l[h] = a[h]; }
#pragma unroll
  for (int msk = 1; msk < 64; msk <<= 1) {
#pragma unroll
    for (int h = 0; h < 8; ++h) l[h] += __shfl_xor(l[h], msk, 64);
  }
#pragma unroll
  for (int h = 0; h < 8; ++h) pb[h * 64 + lane] = a[h] / l[h];
  asm volatile("s_waitcnt lgkmcnt(0)" ::: "memory");
  // ---- PV: lane = e ----
  const float* pr = pb + (lane >> 3) * 64;
  float attn = 0.f;
  for (int k = 0; k < t; ++k) attn = fmaf(pr[k], Vb[k * 65 + lane], attn);

  float y1 = ln64(x + proj_lds(attn, xb, P.saW3, P.sab3, lane), P.g0, P.be0, lane);
  float qc = proj_lds(y1, xb, P.caW0, P.cab0, lane);
  float pa = red8(qc * P.cs1_r);
  float pc = red8(qc * P.cab1_r);
  const float4* wv4 = (const float4*)wv;
  float mc = NEG_INF;
#pragma unroll
  for (int i = 0; i < 16; ++i) {
    float4 wq = wv4[i];
    int k = 4 * i;
    if (k + 0 < t) mc = fmaxf(mc, fmaf(pa, wq.x, pc));
    if (k + 1 < t) mc = fmaxf(mc, fmaf(pa, wq.y, pc));
    if (k + 2 < t) mc = fmaxf(mc, fmaf(pa, wq.z, pc));
    if (k + 3 < t) mc = fmaxf(mc, fmaf(pa, wq.w, pc));
  }
  float lc = 0.f, z = 0.f;
#pragma unroll
  for (int i = 0; i < 16; ++i) {
    float4 wq = wv4[i];
    int k = 4 * i;
    float wk[4] = {wq.x, wq.y, wq.z, wq.w};
#pragma unroll
    for (int j = 0; j < 4; ++j) {
      if (k + j < t) {
        float raw = fmaf(pa, wk[j], pc);
        float pw = expf((raw - mc) * ISQ8);
        lc += pw;
        z = fmaf(pw, wk[j], z);
      }
    }
  }
  float oc = fmaf(z / lc, P.cs2_r, P.cab2_r);
  float y2 = ln64(y1 + proj_lds(oc, xb, P.caW3, P.cab3, lane), P.g1, P.be1, lane);
  float f = fmaxf(proj_lds(y2, xb, P.ffW1, P.ffb1, lane), 0.f);
  float y3 = ln64(y2 + proj_lds(f, xb, P.ffW2, P.ffb2, lane), P.g2, P.be2, lane);
  return y3;
}

__device__ __forceinline__ void build_layer(LayerR& L, int n, int lane,
    const float* sa_W, const float* sa_b, const float* ca_W, const float* ca_b,
    const float* ff_W1, const float* ff_b1, const float* ff_W2, const float* ff_b2,
    const float* ln_g, const float* ln_b) {
  L.saW3 = sa_W + (n * 4 + 3) * 4096; L.sab3 = sa_b + (n * 4 + 3) * 64;
  L.caW0 = ca_W + (n * 4 + 0) * 4096; L.cab0 = ca_b + (n * 4 + 0) * 64;
  L.caW3 = ca_W + (n * 4 + 3) * 4096; L.cab3 = ca_b + (n * 4 + 3) * 64;
  L.ffW1 = ff_W1 + n * 4096;          L.ffb1 = ff_b1 + n * 64;
  L.ffW2 = ff_W2 + n * 4096;          L.ffb2 = ff_b2 + n * 64;
  L.g0 = ln_g + (n * 3 + 0) * 64;     L.be0 = ln_b + (n * 3 + 0) * 64;
  L.g1 = ln_g + (n * 3 + 1) * 64;     L.be1 = ln_b + (n * 3 + 1) * 64;
  L.g2 = ln_g + (n * 3 + 2) * 64;     L.be2 = ln_b + (n * 3 + 2) * 64;
  L.cab1_r = ca_b[(n * 4 + 1) * 64 + lane];
  L.cab2_r = ca_b[(n * 4 + 2) * 64 + lane];
  float c1 = 0.f, c2 = 0.f;
  for (int e = 0; e < 64; ++e) {
    c1 += ca_W[(n * 4 + 1) * 4096 + e * 64 + lane];
    c2 += ca_W[(n * 4 + 2) * 4096 + e * 64 + lane];
  }
  L.cs1_r = c1; L.cs2_r = c2;
}

__global__ __launch_bounds__(1024) void gen_kernel(
    const float* __restrict__ noise, const float* __restrict__ lin_W,
    const float* __restrict__ lin_b, const float* __restrict__ sa_W,
    const float* __restrict__ sa_b, const float* __restrict__ ca_W,
    const float* __restrict__ ca_b, const float* __restrict__ ff_W1,
    const float* __restrict__ ff_b1, const float* __restrict__ ff_W2,
    const float* __restrict__ ff_b2, const float* __restrict__ ln_g,
    const float* __restrict__ ln_b, const float* __restrict__ emb,
    const float* __restrict__ soft_W, const float* __restrict__ soft_b,
    const int* __restrict__ start_id, float* __restrict__ dout,
    float* __restrict__ wsf) {
  const int tid = threadIdx.x, lane = tid & 63, wvid = tid >> 6;
  const int bid = blockIdx.x;

  // ---- workspace: flags in first 8 KB (memset-zeroed), data after ----
  int* wsi = (int*)wsf;
  int* Ff  = wsi;          // [64]  tok_feat ready, target NB
  int* C3f = wsi + 64;     // [64]  vocab-stats counter, last poster (==NVB-1) reduces
  int* Rf  = wsi + 128;    // [64]  m/S/argmax ready, target 1
  int* Af  = wsi + 192;    // [8][64] layer-1 done (per batch, per step), target 4
  int* RRf = wsi + 704;    // [8][64] K1g/V1g row t written, target 1
  float* tokf_g  = wsf + 2048;          // (8,64)
  float* stats_m = wsf + 2560;          // (8,128) use NVB
  float* stats_s = wsf + 3584;          // (8,128)
  int*   stats_i = (int*)(wsf + 4608);  // (8,128)
  float* mS_g    = wsf + 5632;          // (8,2)
  int*   ig_g    = (int*)(wsf + 5648);  // (8)
  float* K1g = wsf + 8192;              // (8,64,64)
  float* V1g = K1g + 8 * 4096;
  float* K2g = V1g + 8 * 4096;
  float* V2g = K2g + 8 * 4096;          // end: 139264 floats (~557 KB)

  __shared__ float lds[26368];          // 105472 B

  if (bid < NBB) {
    // ========== batch sub-block: 1 of 4 per batch, 16 rows, 1 row/wave ==========
    const int b = bid >> 2, sb = bid & 3;
    const int myrow = sb * 16 + wvid;   // row owned by this wave
    float* K1  = lds;                   // 63 rows, stride 65
    float* V1  = lds + 4096;
    float* K2  = lds + 8192;            // tail block only
    float* V2  = lds + 12288;
    float* wvl = lds + 16384;           // (64)
    float* x2s = lds + 16448;           // (64) layer-1 out of row t-1
    int*   igl = (int*)(lds + 16512);   // argmax broadcast
    float* xbuf = lds + 16576;          // 16 waves * 64
    float* pbuf = lds + 17600;          // 16 waves * 512
    float* myxb = xbuf + wvid * 64;
    float* mypb = pbuf + wvid * 512;

    LayerR L0, L1;
    build_layer(L0, 0, lane, sa_W, sa_b, ca_W, ca_b, ff_W1, ff_b1, ff_W2, ff_b2, ln_g, ln_b);
    build_layer(L1, 1, lane, sa_W, sa_b, ca_W, ca_b, ff_W1, ff_b1, ff_W2, ff_b2, ln_g, ln_b);

    float x_r = 0.f, q_r = 0.f;

    if (wvid == 0) {
      // every sub-block computes wvl (cheap, avoids a broadcast)
      float nz = noise[b * 64 + lane];
      float t1v = proj_lds(nz, myxb, lin_W, lin_b, lane);
      wvl[lane] = proj_lds(t1v, myxb, lin_W + 4096, lin_b + 64, lane);
      if (sb == 0) {
        // seed row 0 (pe[0]: sin->0, cos->1); wave 0 of sb0 owns row 0
        float y0 = emb[start_id[0] * 64 + lane] + ((lane & 1) ? 1.0f : 0.0f);
        float q0 = proj_lds(y0, myxb, sa_W, sa_b, lane);
        float k0 = proj_lds(y0, myxb, sa_W + 4096, sa_b + 64, lane);
        float v0 = proj_lds(y0, myxb, sa_W + 2 * 4096, sa_b + 128, lane);
        x_r = y0; q_r = q0;
        cstoref(K1g + b * 4096 + lane, k0);
        cstoref(V1g + b * 4096 + lane, v0);
        postflag(&RRf[b * 64], lane);
      }
    }
    __syncthreads();

    for (int t = 1; t <= 63; ++t) {
      // ---- append row t-1 to the K1/V1 LDS mirror ----
      if (tid == 0) spin_until(&RRf[b * 64 + t - 1], 1);
      __syncthreads();
      if (wvid == 0) K1[(t - 1) * 65 + lane] = cloadf(K1g + b * 4096 + (t - 1) * 64 + lane);
      if (wvid == 1) V1[(t - 1) * 65 + lane] = cloadf(V1g + b * 4096 + (t - 1) * 64 + lane);
      __syncthreads();

      const bool istail = (sb == ((t - 1) >> 4));
      // ---- layer-1: one row per wave, all rows in parallel ----
      if (myrow < t) {
        float out = transformer_row(lane, t, x_r, q_r, K1, V1, wvl, myxb, mypb, L0);
        float k2 = proj_lds(out, myxb, sa_W + 5 * 4096, sa_b + 5 * 64, lane);
        float v2 = proj_lds(out, myxb, sa_W + 6 * 4096, sa_b + 6 * 64, lane);
        cstoref(K2g + b * 4096 + myrow * 64 + lane, k2);
        cstoref(V2g + b * 4096 + myrow * 64 + lane, v2);
        if (istail) { K2[myrow * 65 + lane] = k2; V2[myrow * 65 + lane] = v2; }
        if (myrow == t - 1) x2s[lane] = out;
        __builtin_amdgcn_s_waitcnt(0);  // drain my agent stores
      }
      __syncthreads();
      if (tid == 0)
        __hip_atomic_fetch_add(&Af[b * 64 + t], 1, __ATOMIC_RELAXED, __HIP_MEMORY_SCOPE_AGENT);

      if (istail) {
        // ---- gather non-own K2/V2 rows (parallel across waves), layer-2 on wave 0 ----
        if (tid == 0) spin_until(&Af[b * 64 + t], 4);
        __syncthreads();
        const int lo = sb * 16, hi = lo + 16;
        for (int r = wvid; r < t; r += 16) {
          if (r < lo || r >= hi) {
            K2[r * 65 + lane] = cloadf(K2g + b * 4096 + r * 64 + lane);
            V2[r * 65 + lane] = cloadf(V2g + b * 4096 + r * 64 + lane);
          }
        }
        __syncthreads();
        if (wvid == 0) {
          float x2 = x2s[lane];
          float q2 = proj_lds(x2, myxb, sa_W + 4 * 4096, sa_b + 4 * 64, lane);
          float tf = transformer_row(lane, t, x2, q2, K2, V2, wvl, myxb, mypb, L1);
          cstoref(tokf_g + b * 64 + lane, tf);
          postflag(&Ff[t], lane);
        }
      }

      // ---- new-row phase: block owning row t waits for argmax ----
      if (t < 63 && sb == (t >> 4)) {
        const int ow = t & 15;
        float pev = 0.f;
        if (wvid == ow) {
          double ang = (double)t / pow(10000.0, (double)(lane & 62) / 64.0);
          pev = (lane & 1) ? (float)cos(ang) : (float)sin(ang);
        }
        if (tid == 0) {
          spin_until(&Rf[t], 1);
          igl[0] = cloadi(&ig_g[b]);
        }
        __syncthreads();
        if (wvid == ow) {  // myrow == t for this wave
          float y = emb[igl[0] * 64 + lane] + pev;
          float qn = proj_lds(y, myxb, sa_W, sa_b, lane);
          float kn = proj_lds(y, myxb, sa_W + 4096, sa_b + 64, lane);
          float vn = proj_lds(y, myxb, sa_W + 2 * 4096, sa_b + 128, lane);
          x_r = y; q_r = qn;
          cstoref(K1g + b * 4096 + t * 64 + lane, kn);
          cstoref(V1g + b * 4096 + t * 64 + lane, vn);
          postflag(&RRf[b * 64 + t], lane);
        }
        __syncthreads();
      }
    }
  } else {
    // =================== vocab block: LDS-resident 397-column slice ===================
    const int jb = bid - NBB;
    const int v = jb * VCOLS + tid;
    const bool valid = (tid < VCOLS) && (v < Vc);
    float* sW  = lds;                   // (64, 397) LDS-resident soft_W slice
    float* f2  = lds + 25408;           // (64,8) ftile transposed, e*8+b
    float* sm  = lds + 25920;           // (16,8)
    int*   si  = (int*)(lds + 26048);
    float* ssm = lds + 26176;           // (16,8)
    float* bmx = lds + 26304;           // (8)
    int*   bix = (int*)(lds + 26312);
    float* msl = lds + 26320;           // (16)
    int*   red = (int*)(lds + 26336);
    float sb = valid ? soft_b[v] : 0.f;

    // one-time stage of this block's soft_W slice into LDS (~102 KB)
    if (tid < VCOLS) {
      for (int e = 0; e < 64; ++e)
        sW[e * VCOLS + tid] = (v < Vc) ? soft_W[e * Vc + v] : 0.f;
    }
    __syncthreads();

    for (int t = 1; t <= 63; ++t) {
      if (tid == 0) spin_until(&Ff[t], NB);
      __syncthreads();
      if (tid < 512) f2[tid] = cloadf(&tokf_g[(tid & 7) * 64 + (tid >> 3)]);
      __syncthreads();
      float lg[8];
#pragma unroll
      for (int b = 0; b < 8; ++b) lg[b] = valid ? sb : NEG_INF;
      if (valid) {
        const float4* f4 = (const float4*)f2;
        const float* col = sW + tid;
#pragma unroll 8
        for (int e = 0; e < 64; ++e) {
          float wc = col[e * VCOLS];
          float4 fa = f4[2 * e], fb = f4[2 * e + 1];
          lg[0] = fmaf(fa.x, wc, lg[0]);
          lg[1] = fmaf(fa.y, wc, lg[1]);
          lg[2] = fmaf(fa.z, wc, lg[2]);
          lg[3] = fmaf(fa.w, wc, lg[3]);
          lg[4] = fmaf(fb.x, wc, lg[4]);
          lg[5] = fmaf(fb.y, wc, lg[5]);
          lg[6] = fmaf(fb.z, wc, lg[6]);
          lg[7] = fmaf(fb.w, wc, lg[7]);
        }
      }
#pragma unroll
      for (int b = 0; b < 8; ++b) {
        float m = lg[b]; int ix = valid ? v : 0x7fffffff;
#pragma unroll
        for (int msk = 1; msk < 64; msk <<= 1) {
          float om = __shfl_xor(m, msk, 64);
          int oi = __shfl_xor(ix, msk, 64);
          if (om > m || (om == m && oi < ix)) { m = om; ix = oi; }
        }
        if (lane == 0) { sm[wvid * 8 + b] = m; si[wvid * 8 + b] = ix; }
      }
      __syncthreads();
      if (tid < 8) {
        float m = NEG_INF; int ix = 0x7fffffff;
        for (int wv = 0; wv < 16; ++wv) {
          float om = sm[wv * 8 + tid]; int oi = si[wv * 8 + tid];
          if (om > m || (om == m && oi < ix)) { m = om; ix = oi; }
        }
        bmx[tid] = m; bix[tid] = ix;
      }
      __syncthreads();
#pragma unroll
      for (int b = 0; b < 8; ++b) {
        float c = valid ? expf(lg[b] - bmx[b]) : 0.f;
        float s = wsum64(c);
        if (lane == 0) ssm[wvid * 8 + b] = s;
      }
      __syncthreads();
      if (wvid == 0) {
        if (lane < 8) {
          float s = 0.f;
          for (int wv = 0; wv < 16; ++wv) s += ssm[wv * 8 + lane];
          cstoref(&stats_m[lane * 128 + jb], bmx[lane]);
          cstoref(&stats_s[lane * 128 + jb], s);
          cstorei(&stats_i[lane * 128 + jb], bix[lane]);
        }
        __builtin_amdgcn_s_waitcnt(0);  // stats at coherence point before counting in
        if (lane == 0)
          red[0] = __hip_atomic_fetch_add(&C3f[t], 1, __ATOMIC_RELAXED, __HIP_MEMORY_SCOPE_AGENT);
      }
      __syncthreads();
      if (red[0] == NVB - 1) {
        // last-arriving vocab block reduces all 8 batches (no leader poll latency)
        if (wvid < 8) {
          const int b2 = wvid;
          float mA = cloadf(&stats_m[b2 * 128 + lane]);
          float sA = cloadf(&stats_s[b2 * 128 + lane]);
          int   iA = cloadi(&stats_i[b2 * 128 + lane]);
          const bool a2 = lane < (NVB - 64);
          float mB = a2 ? cloadf(&stats_m[b2 * 128 + 64 + lane]) : NEG_INF;
          float sB = a2 ? cloadf(&stats_s[b2 * 128 + 64 + lane]) : 0.f;
          int   iB = a2 ? cloadi(&stats_i[b2 * 128 + 64 + lane]) : 0x7fffffff;
          float mg = mA; int ig = iA;
          if (mB > mg || (mB == mg && iB < ig)) { mg = mB; ig = iB; }
#pragma unroll
          for (int msk = 1; msk < 64; msk <<= 1) {
            float om = __shfl_xor(mg, msk, 64);
            int oi = __shfl_xor(ig, msk, 64);
            if (om > mg || (om == mg && oi < ig)) { mg = om; ig = oi; }
          }
          float part = sA * expf(mA - mg) + (a2 ? sB * expf(mB - mg) : 0.f);
          float S = wsum64(part);
          if (lane == 0) {
            cstoref(&mS_g[b2 * 2], mg);
            cstoref(&mS_g[b2 * 2 + 1], S);
            cstorei(&ig_g[b2], ig);
          }
          __builtin_amdgcn_s_waitcnt(0);  // each reducing wave drains its own stores
        }
        __syncthreads();
        if (tid == 0)
          __hip_atomic_fetch_add(&Rf[t], 1, __ATOMIC_RELAXED, __HIP_MEMORY_SCOPE_AGENT);
      }
      if (tid == 0) spin_until(&Rf[t], 1);
      __syncthreads();
      if (tid < 16) msl[tid] = cloadf(&mS_g[tid]);
      __syncthreads();
      if (valid) {
        long base = (long)(t - 1) * Vc + v;
#pragma unroll
        for (int b = 0; b < 8; ++b)
          dout[(long)b * 63 * Vc + base] = expf(lg[b] - msl[2 * b]) / msl[2 * b + 1];
      }
      __syncthreads();
    }
  }
}

extern "C" void kernel_launch(void* const* d_in, const int* in_sizes, int n_in,
                              void* d_out, int out_size, void* d_ws, size_t ws_size,
                              hipStream_t stream) {
  (void)in_sizes; (void)n_in; (void)out_size; (void)ws_size;
  hipMemsetAsync(d_ws, 0, 8192, stream);  // zero all flag arrays
  gen_kernel<<<dim3(NBB + NVB), dim3(1024), 0, stream>>>(
      (const float*)d_in[0], (const float*)d_in[1], (const float*)d_in[2],
      (const float*)d_in[3], (const float*)d_in[4], (const float*)d_in[5],
      (const float*)d_in[6], (const float*)d_in[7], (const float*)d_in[8],
      (const float*)d_in[9], (const float*)d_in[10], (const float*)d_in[11],
      (const float*)d_in[12], (const float*)d_in[13], (const float*)d_in[14],
      (const float*)d_in[15], (const int*)d_in[16],
      (float*)d_out, (float*)d_ws);
}

// Round 5
// 22751.704 us; speedup vs baseline: 1.6426x; 1.0546x over previous
//
#include <hip/hip_runtime.h>
#include <math.h>

#define Vc 50257
#define NEG_INF (-__builtin_inff())
#define VCOLS 397   // vocab columns per vocab block (LDS-resident slice)
#define NVB 127     // 127*397 = 50419 >= 50257
#define NB  8       // batches
#define NBB 32      // batch blocks: 4 per batch, 16 rows each, 1 row per wave
#define GUARD (1 << 21)

// ---------------- wave-level helpers ----------------

__device__ __forceinline__ float wsum64(float v) {
#pragma unroll
  for (int m = 32; m >= 1; m >>= 1) v += __shfl_xor(v, m, 64);
  return v;
}

__device__ __forceinline__ float red8(float v) {
  v += __shfl_xor(v, 1, 64);
  v += __shfl_xor(v, 2, 64);
  v += __shfl_xor(v, 4, 64);
  return v;
}

// out[lane] = bias[lane] + sum_e x[e]*W[e*64+lane]; x broadcast via LDS float4 reads
__device__ __forceinline__ float proj_lds(float xv, float* xb,
                                          const float* __restrict__ W,
                                          const float* __restrict__ bias, int lane) {
  xb[lane] = xv;
  asm volatile("s_waitcnt lgkmcnt(0)" ::: "memory");
  float acc = bias[lane];
  const float4* x4 = (const float4*)xb;
#pragma unroll
  for (int i = 0; i < 16; ++i) {
    float4 xc = x4[i];
    acc = fmaf(xc.x, W[(4 * i + 0) * 64 + lane], acc);
    acc = fmaf(xc.y, W[(4 * i + 1) * 64 + lane], acc);
    acc = fmaf(xc.z, W[(4 * i + 2) * 64 + lane], acc);
    acc = fmaf(xc.w, W[(4 * i + 3) * 64 + lane], acc);
  }
  asm volatile("" ::: "memory");
  return acc;
}

__device__ __forceinline__ float ln64(float xv, const float* __restrict__ g,
                                      const float* __restrict__ b, int lane) {
  float mean = wsum64(xv) * 0.015625f;
  float d = xv - mean;
  float var = wsum64(d * d) * 0.015625f;
  float r = 1.0f / sqrtf(var + 1e-5f);
  return d * r * g[lane] + b[lane];
}

// ------------- coherent cross-block access: relaxed agent atomics -------------

__device__ __forceinline__ float cloadf(const float* p) {
  return __hip_atomic_load(p, __ATOMIC_RELAXED, __HIP_MEMORY_SCOPE_AGENT);
}
__device__ __forceinline__ int cloadi(const int* p) {
  return __hip_atomic_load(p, __ATOMIC_RELAXED, __HIP_MEMORY_SCOPE_AGENT);
}
__device__ __forceinline__ void cstoref(float* p, float v) {
  __hip_atomic_store(p, v, __ATOMIC_RELAXED, __HIP_MEMORY_SCOPE_AGENT);
}
__device__ __forceinline__ void cstorei(int* p, int v) {
  __hip_atomic_store(p, v, __ATOMIC_RELAXED, __HIP_MEMORY_SCOPE_AGENT);
}
__device__ __forceinline__ void postflag(int* f, int lane) {
  __builtin_amdgcn_s_waitcnt(0);
  if (lane == 0) __hip_atomic_fetch_add(f, 1, __ATOMIC_RELAXED, __HIP_MEMORY_SCOPE_AGENT);
}

// VALU burn: keeps the SIMD issuing while we wait (anti-downclock).
__device__ __forceinline__ void fma_burst(float& d0, float& d1, float& d2, float& d3) {
#pragma unroll
  for (int i = 0; i < 16; ++i) {
    d0 = fmaf(d0, 1.0000001f, 1.0f);
    d1 = fmaf(d1, 1.0000002f, 1.0f);
    d2 = fmaf(d2, 1.0000003f, 1.0f);
    d3 = fmaf(d3, 1.0000004f, 1.0f);
  }
}

// Whole-block wait: wave 0 polls the agent-scope flag (sole MALL poller),
// other waves FMA-spin on an LDS release counter. All SIMDs stay busy.
// Bounded: on guard trip we proceed (bench reports absmax failure, no GPU hang).
__device__ __forceinline__ void block_wait(int* gf, int target, int* lrel, int tok,
                                           int wvid, int lane) {
  float d0 = 0.f, d1 = 0.f, d2 = 0.f, d3 = 0.f;
  int guard = GUARD;
  if (wvid == 0) {
    while (__hip_atomic_load(gf, __ATOMIC_RELAXED, __HIP_MEMORY_SCOPE_AGENT) < target) {
      fma_burst(d0, d1, d2, d3);
      if (--guard == 0) break;
    }
    __builtin_amdgcn_s_waitcnt(0);
    if (lane == 0)
      __hip_atomic_store(lrel, tok, __ATOMIC_RELAXED, __HIP_MEMORY_SCOPE_WORKGROUP);
  } else {
    while (__hip_atomic_load(lrel, __ATOMIC_RELAXED, __HIP_MEMORY_SCOPE_WORKGROUP) < tok) {
      fma_burst(d0, d1, d2, d3);
      if (--guard == 0) break;
    }
  }
  asm volatile("" :: "v"(d0), "v"(d1), "v"(d2), "v"(d3));
  __syncthreads();
}

struct LayerR {
  const float *saW3, *sab3, *caW0, *cab0, *caW3, *cab3,
              *ffW1, *ffb1, *ffW2, *ffb2, *g0, *be0, *g1, *be1, *g2, *be2;
  float cs1_r, cs2_r, cab1_r, cab2_r;
};

// One wave, one row. K/V in LDS with row stride 65 (bank = (k+e)%32 -> 2-way, free).
__device__ float transformer_row(int lane, int t, float x, float q,
                                 const float* Kb, const float* Vb,
                                 const float* wv, float* xb, float* pb,
                                 const LayerR& P) {
  const float ISQ8 = 0.35355339059327373f;  // 1/sqrt(8)
  // ---- scores: lane = k ----
  xb[lane] = q;
  asm volatile("s_waitcnt lgkmcnt(0)" ::: "memory");
  float a[8] = {0.f, 0.f, 0.f, 0.f, 0.f, 0.f, 0.f, 0.f};
  const float* Krow = Kb + lane * 65;
  const float4* xq4 = (const float4*)xb;
#pragma unroll
  for (int i = 0; i < 16; ++i) {
    float4 xc = xq4[i];
    a[i >> 1] = fmaf(xc.x, Krow[4 * i + 0], a[i >> 1]);
    a[i >> 1] = fmaf(xc.y, Krow[4 * i + 1], a[i >> 1]);
    a[i >> 1] = fmaf(xc.z, Krow[4 * i + 2], a[i >> 1]);
    a[i >> 1] = fmaf(xc.w, Krow[4 * i + 3], a[i >> 1]);
  }
  const bool act = lane < t;
  float m[8];
#pragma unroll
  for (int h = 0; h < 8; ++h) { a[h] = act ? a[h] * ISQ8 : NEG_INF; m[h] = a[h]; }
#pragma unroll
  for (int msk = 1; msk < 64; msk <<= 1) {
#pragma unroll
    for (int h = 0; h < 8; ++h) m[h] = fmaxf(m[h], __shfl_xor(m[h], msk, 64));
  }
  float l[8];
#pragma unroll
  for (int h = 0; h < 8; ++h) { a[h] = act ? expf(a[h] - m[h]) : 0.f; l[h] = a[h]; }
#pragma unroll
  for (int msk = 1; msk < 64; msk <<= 1) {
#pragma unroll
    for (int h = 0; h < 8; ++h) l[h] += __shfl_xor(l[h], msk, 64);
  }
#pragma unroll
  for (int h = 0; h < 8; ++h) pb[h * 64 + lane] = a[h] / l[h];
  asm volatile("s_waitcnt lgkmcnt(0)" ::: "memory");
  // ---- PV: lane = e ----
  const float* pr = pb + (lane >> 3) * 64;
  float attn = 0.f;
  for (int k = 0; k < t; ++k) attn = fmaf(pr[k], Vb[k * 65 + lane], attn);

  float y1 = ln64(x + proj_lds(attn, xb, P.saW3, P.sab3, lane), P.g0, P.be0, lane);
  float qc = proj_lds(y1, xb, P.caW0, P.cab0, lane);
  float pa = red8(qc * P.cs1_r);
  float pc = red8(qc * P.cab1_r);
  const float4* wv4 = (const float4*)wv;
  float mc = NEG_INF;
#pragma unroll
  for (int i = 0; i < 16; ++i) {
    float4 wq = wv4[i];
    int k = 4 * i;
    if (k + 0 < t) mc = fmaxf(mc, fmaf(pa, wq.x, pc));
    if (k + 1 < t) mc = fmaxf(mc, fmaf(pa, wq.y, pc));
    if (k + 2 < t) mc = fmaxf(mc, fmaf(pa, wq.z, pc));
    if (k + 3 < t) mc = fmaxf(mc, fmaf(pa, wq.w, pc));
  }
  float lc = 0.f, z = 0.f;
#pragma unroll
  for (int i = 0; i < 16; ++i) {
    float4 wq = wv4[i];
    int k = 4 * i;
    float wk[4] = {wq.x, wq.y, wq.z, wq.w};
#pragma unroll
    for (int j = 0; j < 4; ++j) {
      if (k + j < t) {
        float raw = fmaf(pa, wk[j], pc);
        float pw = expf((raw - mc) * ISQ8);
        lc += pw;
        z = fmaf(pw, wk[j], z);
      }
    }
  }
  float oc = fmaf(z / lc, P.cs2_r, P.cab2_r);
  float y2 = ln64(y1 + proj_lds(oc, xb, P.caW3, P.cab3, lane), P.g1, P.be1, lane);
  float f = fmaxf(proj_lds(y2, xb, P.ffW1, P.ffb1, lane), 0.f);
  float y3 = ln64(y2 + proj_lds(f, xb, P.ffW2, P.ffb2, lane), P.g2, P.be2, lane);
  return y3;
}

__device__ __forceinline__ void build_layer(LayerR& L, int n, int lane,
    const float* sa_W, const float* sa_b, const float* ca_W, const float* ca_b,
    const float* ff_W1, const float* ff_b1, const float* ff_W2, const float* ff_b2,
    const float* ln_g, const float* ln_b) {
  L.saW3 = sa_W + (n * 4 + 3) * 4096; L.sab3 = sa_b + (n * 4 + 3) * 64;
  L.caW0 = ca_W + (n * 4 + 0) * 4096; L.cab0 = ca_b + (n * 4 + 0) * 64;
  L.caW3 = ca_W + (n * 4 + 3) * 4096; L.cab3 = ca_b + (n * 4 + 3) * 64;
  L.ffW1 = ff_W1 + n * 4096;          L.ffb1 = ff_b1 + n * 64;
  L.ffW2 = ff_W2 + n * 4096;          L.ffb2 = ff_b2 + n * 64;
  L.g0 = ln_g + (n * 3 + 0) * 64;     L.be0 = ln_b + (n * 3 + 0) * 64;
  L.g1 = ln_g + (n * 3 + 1) * 64;     L.be1 = ln_b + (n * 3 + 1) * 64;
  L.g2 = ln_g + (n * 3 + 2) * 64;     L.be2 = ln_b + (n * 3 + 2) * 64;
  L.cab1_r = ca_b[(n * 4 + 1) * 64 + lane];
  L.cab2_r = ca_b[(n * 4 + 2) * 64 + lane];
  float c1 = 0.f, c2 = 0.f;
  for (int e = 0; e < 64; ++e) {
    c1 += ca_W[(n * 4 + 1) * 4096 + e * 64 + lane];
    c2 += ca_W[(n * 4 + 2) * 4096 + e * 64 + lane];
  }
  L.cs1_r = c1; L.cs2_r = c2;
}

__global__ __launch_bounds__(1024) void gen_kernel(
    const float* __restrict__ noise, const float* __restrict__ lin_W,
    const float* __restrict__ lin_b, const float* __restrict__ sa_W,
    const float* __restrict__ sa_b, const float* __restrict__ ca_W,
    const float* __restrict__ ca_b, const float* __restrict__ ff_W1,
    const float* __restrict__ ff_b1, const float* __restrict__ ff_W2,
    const float* __restrict__ ff_b2, const float* __restrict__ ln_g,
    const float* __restrict__ ln_b, const float* __restrict__ emb,
    const float* __restrict__ soft_W, const float* __restrict__ soft_b,
    const int* __restrict__ start_id, float* __restrict__ dout,
    float* __restrict__ wsf) {
  const int tid = threadIdx.x, lane = tid & 63, wvid = tid >> 6;
  const int bid = blockIdx.x;

  // ---- workspace: flags in first 8 KB (memset-zeroed), data after ----
  int* wsi = (int*)wsf;
  int* Ff  = wsi;          // [64]  tok_feat ready, target NB
  int* C3f = wsi + 64;     // [64]  vocab-stats counter, last poster (==NVB-1) reduces
  int* Rf  = wsi + 128;    // [64]  m/S/argmax ready, target 1
  int* Af  = wsi + 192;    // [8][64] layer-1 done (per batch, per step), target 4
  float* tokf_g  = wsf + 2048;          // (8,64)
  float* stats_m = wsf + 2560;          // (8,128) use NVB
  float* stats_s = wsf + 3584;          // (8,128)
  int*   stats_i = (int*)(wsf + 4608);  // (8,128)
  float* mS_g    = wsf + 5632;          // (8,2)
  int*   ig_g    = (int*)(wsf + 5648);  // (8)
  float* K2g = wsf + 8192;              // (8,64,64)
  float* V2g = K2g + 8 * 4096;

  __shared__ float lds[26368];          // 105472 B

  if (bid < NBB) {
    // ========== batch sub-block: 1 of 4 per batch, 16 rows, 1 row/wave ==========
    const int b = bid >> 2, sb = bid & 3;
    const int myrow = sb * 16 + wvid;   // row owned by this wave
    float* K1  = lds;                   // 63 rows, stride 65 (local mirror, locally built)
    float* V1  = lds + 4096;
    float* K2  = lds + 8192;            // tail block only
    float* V2  = lds + 12288;
    float* wvl = lds + 16384;           // (64)
    float* x2s = lds + 16448;           // (64) layer-1 out of row t-1
    float* ynew = lds + 16512;          // (64) new row broadcast
    float* xbuf = lds + 16576;          // 16 waves * 64
    float* pbuf = lds + 17600;          // 16 waves * 512
    int* lrelA = (int*)(lds + 25792);   // LDS release counters for block_wait
    int* lrelR = (int*)(lds + 25793);
    float* myxb = xbuf + wvid * 64;
    float* mypb = pbuf + wvid * 512;

    LayerR L0, L1;
    build_layer(L0, 0, lane, sa_W, sa_b, ca_W, ca_b, ff_W1, ff_b1, ff_W2, ff_b2, ln_g, ln_b);
    build_layer(L1, 1, lane, sa_W, sa_b, ca_W, ca_b, ff_W1, ff_b1, ff_W2, ff_b2, ln_g, ln_b);

    float x_r = 0.f, q_r = 0.f;
    if (tid == 0) { *lrelA = 0; *lrelR = 0; }

    if (wvid == 0) {
      // every sub-block computes wvl + seed row locally (no cross-block handoff)
      float nz = noise[b * 64 + lane];
      float t1v = proj_lds(nz, myxb, lin_W, lin_b, lane);
      wvl[lane] = proj_lds(t1v, myxb, lin_W + 4096, lin_b + 64, lane);
      float y0 = emb[start_id[0] * 64 + lane] + ((lane & 1) ? 1.0f : 0.0f);
      float k0 = proj_lds(y0, myxb, sa_W + 4096, sa_b + 64, lane);
      float v0 = proj_lds(y0, myxb, sa_W + 2 * 4096, sa_b + 128, lane);
      K1[lane] = k0; V1[lane] = v0;
      if (sb == 0) {  // owner of row 0
        x_r = y0;
        q_r = proj_lds(y0, myxb, sa_W, sa_b, lane);
      }
    }
    __syncthreads();

    for (int t = 1; t <= 63; ++t) {
      const bool istail = (sb == ((t - 1) >> 4));
      // ---- layer-1: one row per wave, all rows in parallel ----
      if (myrow < t) {
        float out = transformer_row(lane, t, x_r, q_r, K1, V1, wvl, myxb, mypb, L0);
        float k2 = proj_lds(out, myxb, sa_W + 5 * 4096, sa_b + 5 * 64, lane);
        float v2 = proj_lds(out, myxb, sa_W + 6 * 4096, sa_b + 6 * 64, lane);
        cstoref(K2g + b * 4096 + myrow * 64 + lane, k2);
        cstoref(V2g + b * 4096 + myrow * 64 + lane, v2);
        if (istail) { K2[myrow * 65 + lane] = k2; V2[myrow * 65 + lane] = v2; }
        if (myrow == t - 1) x2s[lane] = out;
        __builtin_amdgcn_s_waitcnt(0);  // drain my agent stores
      }
      __syncthreads();
      if (tid == 0)
        __hip_atomic_fetch_add(&Af[b * 64 + t], 1, __ATOMIC_RELAXED, __HIP_MEMORY_SCOPE_AGENT);

      if (istail) {
        // ---- gather non-own K2/V2 rows (parallel across waves), layer-2 on wave 0 ----
        block_wait(&Af[b * 64 + t], 4, lrelA, t, wvid, lane);
        const int lo = sb * 16, hi = lo + 16;
        for (int r = wvid; r < t; r += 16) {
          if (r < lo || r >= hi) {
            K2[r * 65 + lane] = cloadf(K2g + b * 4096 + r * 64 + lane);
            V2[r * 65 + lane] = cloadf(V2g + b * 4096 + r * 64 + lane);
          }
        }
        __syncthreads();
        if (wvid == 0) {
          float x2 = x2s[lane];
          float q2 = proj_lds(x2, myxb, sa_W + 4 * 4096, sa_b + 4 * 64, lane);
          float tf = transformer_row(lane, t, x2, q2, K2, V2, wvl, myxb, mypb, L1);
          cstoref(tokf_g + b * 64 + lane, tf);
          postflag(&Ff[t], lane);
        }
      }

      // ---- new-row phase: every sub-block rebuilds row t locally after argmax ----
      if (t < 63) {
        float pev = 0.f;
        if (wvid == 0) {  // pe[t] — argmax-independent, overlaps the wait below
          double ang = (double)t / pow(10000.0, (double)(lane & 62) / 64.0);
          pev = (lane & 1) ? (float)cos(ang) : (float)sin(ang);
        }
        block_wait(&Rf[t], 1, lrelR, t, wvid, lane);
        if (wvid == 0) {
          int ig = cloadi(&ig_g[b]);
          float y = emb[ig * 64 + lane] + pev;
          float kn = proj_lds(y, myxb, sa_W + 4096, sa_b + 64, lane);
          float vn = proj_lds(y, myxb, sa_W + 2 * 4096, sa_b + 128, lane);
          K1[t * 65 + lane] = kn;
          V1[t * 65 + lane] = vn;
          ynew[lane] = y;
        }
        __syncthreads();
        if (sb == (t >> 4) && wvid == (t & 15)) {  // owner wave of row t
          x_r = ynew[lane];
          q_r = proj_lds(x_r, myxb, sa_W, sa_b, lane);
        }
      }
    }
  } else {
    // =================== vocab block: LDS-resident 397-column slice ===================
    const int jb = bid - NBB;
    const int v = jb * VCOLS + tid;
    const bool valid = (tid < VCOLS) && (v < Vc);
    float* sW  = lds;                   // (64, 397) LDS-resident soft_W slice
    float* f2  = lds + 25408;           // (64,8) ftile transposed, e*8+b
    float* sm  = lds + 25920;           // (16,8)
    int*   si  = (int*)(lds + 26048);
    float* ssm = lds + 26176;           // (16,8)
    float* bmx = lds + 26304;           // (8)
    int*   bix = (int*)(lds + 26312);
    float* msl = lds + 26320;           // (16)
    int*   red = (int*)(lds + 26336);
    int* lrelF = (int*)(lds + 26344);
    int* lrelR2 = (int*)(lds + 26345);
    float sb = valid ? soft_b[v] : 0.f;

    if (tid == 0) { *lrelF = 0; *lrelR2 = 0; }
    // one-time stage of this block's soft_W slice into LDS (~102 KB)
    if (tid < VCOLS) {
      for (int e = 0; e < 64; ++e)
        sW[e * VCOLS + tid] = (v < Vc) ? soft_W[e * Vc + v] : 0.f;
    }
    __syncthreads();

    for (int t = 1; t <= 63; ++t) {
      block_wait(&Ff[t], NB, lrelF, t, wvid, lane);
      if (tid < 512) f2[tid] = cloadf(&tokf_g[(tid & 7) * 64 + (tid >> 3)]);
      __syncthreads();
      float lg[8];
#pragma unroll
      for (int b = 0; b < 8; ++b) lg[b] = valid ? sb : NEG_INF;
      if (valid) {
        const float4* f4 = (const float4*)f2;
        const float* col = sW + tid;
#pragma unroll 8
        for (int e = 0; e < 64; ++e) {
          float wc = col[e * VCOLS];
          float4 fa = f4[2 * e], fb = f4[2 * e + 1];
          lg[0] = fmaf(fa.x, wc, lg[0]);
          lg[1] = fmaf(fa.y, wc, lg[1]);
          lg[2] = fmaf(fa.z, wc, lg[2]);
          lg[3] = fmaf(fa.w, wc, lg[3]);
          lg[4] = fmaf(fb.x, wc, lg[4]);
          lg[5] = fmaf(fb.y, wc, lg[5]);
          lg[6] = fmaf(fb.z, wc, lg[6]);
          lg[7] = fmaf(fb.w, wc, lg[7]);
        }
      }
#pragma unroll
      for (int b = 0; b < 8; ++b) {
        float m = lg[b]; int ix = valid ? v : 0x7fffffff;
#pragma unroll
        for (int msk = 1; msk < 64; msk <<= 1) {
          float om = __shfl_xor(m, msk, 64);
          int oi = __shfl_xor(ix, msk, 64);
          if (om > m || (om == m && oi < ix)) { m = om; ix = oi; }
        }
        if (lane == 0) { sm[wvid * 8 + b] = m; si[wvid * 8 + b] = ix; }
      }
      __syncthreads();
      if (tid < 8) {
        float m = NEG_INF; int ix = 0x7fffffff;
        for (int wv = 0; wv < 16; ++wv) {
          float om = sm[wv * 8 + tid]; int oi = si[wv * 8 + tid];
          if (om > m || (om == m && oi < ix)) { m = om; ix = oi; }
        }
        bmx[tid] = m; bix[tid] = ix;
      }
      __syncthreads();
#pragma unroll
      for (int b = 0; b < 8; ++b) {
        float c = valid ? expf(lg[b] - bmx[b]) : 0.f;
        float s = wsum64(c);
        if (lane == 0) ssm[wvid * 8 + b] = s;
      }
      __syncthreads();
      if (wvid == 0) {
        if (lane < 8) {
          float s = 0.f;
          for (int wv = 0; wv < 16; ++wv) s += ssm[wv * 8 + lane];
          cstoref(&stats_m[lane * 128 + jb], bmx[lane]);
          cstoref(&stats_s[lane * 128 + jb], s);
          cstorei(&stats_i[lane * 128 + jb], bix[lane]);
        }
        __builtin_amdgcn_s_waitcnt(0);  // stats at coherence point before counting in
        if (lane == 0)
          red[0] = __hip_atomic_fetch_add(&C3f[t], 1, __ATOMIC_RELAXED, __HIP_MEMORY_SCOPE_AGENT);
      }
      __syncthreads();
      if (red[0] == NVB - 1) {
        // last-arriving vocab block reduces all 8 batches (no leader poll latency)
        if (wvid < 8) {
          const int b2 = wvid;
          float mA = cloadf(&stats_m[b2 * 128 + lane]);
          float sA = cloadf(&stats_s[b2 * 128 + lane]);
          int   iA = cloadi(&stats_i[b2 * 128 + lane]);
          const bool a2 = lane < (NVB - 64);
          float mB = a2 ? cloadf(&stats_m[b2 * 128 + 64 + lane]) : NEG_INF;
          float sB = a2 ? cloadf(&stats_s[b2 * 128 + 64 + lane]) : 0.f;
          int   iB = a2 ? cloadi(&stats_i[b2 * 128 + 64 + lane]) : 0x7fffffff;
          float mg = mA; int ig = iA;
          if (mB > mg || (mB == mg && iB < ig)) { mg = mB; ig = iB; }
#pragma unroll
          for (int msk = 1; msk < 64; msk <<= 1) {
            float om = __shfl_xor(mg, msk, 64);
            int oi = __shfl_xor(ig, msk, 64);
            if (om > mg || (om == mg && oi < ig)) { mg = om; ig = oi; }
          }
          float part = sA * expf(mA - mg) + (a2 ? sB * expf(mB - mg) : 0.f);
          float S = wsum64(part);
          if (lane == 0) {
            cstoref(&mS_g[b2 * 2], mg);
            cstoref(&mS_g[b2 * 2 + 1], S);
            cstorei(&ig_g[b2], ig);
          }
          __builtin_amdgcn_s_waitcnt(0);  // each reducing wave drains its own stores
        }
        __syncthreads();
        if (tid == 0)
          __hip_atomic_fetch_add(&Rf[t], 1, __ATOMIC_RELAXED, __HIP_MEMORY_SCOPE_AGENT);
      }
      block_wait(&Rf[t], 1, lrelR2, t, wvid, lane);
      if (tid < 16) msl[tid] = cloadf(&mS_g[tid]);
      __syncthreads();
      if (valid) {
        long base = (long)(t - 1) * Vc + v;
#pragma unroll
        for (int b = 0; b < 8; ++b)
          dout[(long)b * 63 * Vc + base] = expf(lg[b] - msl[2 * b]) / msl[2 * b + 1];
      }
      __syncthreads();
    }
  }
}

extern "C" void kernel_launch(void* const* d_in, const int* in_sizes, int n_in,
                              void* d_out, int out_size, void* d_ws, size_t ws_size,
                              hipStream_t stream) {
  (void)in_sizes; (void)n_in; (void)out_size; (void)ws_size;
  hipMemsetAsync(d_ws, 0, 8192, stream);  // zero all flag arrays
  gen_kernel<<<dim3(NBB + NVB), dim3(1024), 0, stream>>>(
      (const float*)d_in[0], (const float*)d_in[1], (const float*)d_in[2],
      (const float*)d_in[3], (const float*)d_in[4], (const float*)d_in[5],
      (const float*)d_in[6], (const float*)d_in[7], (const float*)d_in[8],
      (const float*)d_in[9], (const float*)d_in[10], (const float*)d_in[11],
      (const float*)d_in[12], (const float*)d_in[13], (const float*)d_in[14],
      (const float*)d_in[15], (const int*)d_in[16],
      (float*)d_out, (float*)d_ws);
}

// Round 6
// 22591.360 us; speedup vs baseline: 1.6543x; 1.0071x over previous
//
#include <hip/hip_runtime.h>
#include <math.h>

#define Vc 50257
#define NEG_INF (-__builtin_inff())
#define VCOLS 397   // vocab columns per vocab block (LDS-resident slice)
#define NVB 127     // 127*397 = 50419 >= 50257
#define NB  8       // batches
#define NBB 32      // batch blocks: 4 per batch, 16 rows each, 1 row per wave
#define GUARD (1 << 21)

// ---------------- wave-level helpers ----------------

__device__ __forceinline__ float wsum64(float v) {
#pragma unroll
  for (int m = 32; m >= 1; m >>= 1) v += __shfl_xor(v, m, 64);
  return v;
}

__device__ __forceinline__ float red8(float v) {
  v += __shfl_xor(v, 1, 64);
  v += __shfl_xor(v, 2, 64);
  v += __shfl_xor(v, 4, 64);
  return v;
}

// out[lane] = bias[lane] + sum_e x[e]*W[e*64+lane]; x broadcast via LDS float4 reads
__device__ __forceinline__ float proj_lds(float xv, float* xb,
                                          const float* __restrict__ W,
                                          const float* __restrict__ bias, int lane) {
  xb[lane] = xv;
  asm volatile("s_waitcnt lgkmcnt(0)" ::: "memory");
  float acc = bias[lane];
  const float4* x4 = (const float4*)xb;
#pragma unroll
  for (int i = 0; i < 16; ++i) {
    float4 xc = x4[i];
    acc = fmaf(xc.x, W[(4 * i + 0) * 64 + lane], acc);
    acc = fmaf(xc.y, W[(4 * i + 1) * 64 + lane], acc);
    acc = fmaf(xc.z, W[(4 * i + 2) * 64 + lane], acc);
    acc = fmaf(xc.w, W[(4 * i + 3) * 64 + lane], acc);
  }
  asm volatile("" ::: "memory");
  return acc;
}

__device__ __forceinline__ float ln64(float xv, const float* __restrict__ g,
                                      const float* __restrict__ b, int lane) {
  float mean = wsum64(xv) * 0.015625f;
  float d = xv - mean;
  float var = wsum64(d * d) * 0.015625f;
  float r = 1.0f / sqrtf(var + 1e-5f);
  return d * r * g[lane] + b[lane];
}

// ------------- coherent cross-block access: relaxed agent atomics -------------

__device__ __forceinline__ float cloadf(const float* p) {
  return __hip_atomic_load(p, __ATOMIC_RELAXED, __HIP_MEMORY_SCOPE_AGENT);
}
__device__ __forceinline__ int cloadi(const int* p) {
  return __hip_atomic_load(p, __ATOMIC_RELAXED, __HIP_MEMORY_SCOPE_AGENT);
}
__device__ __forceinline__ void cstoref(float* p, float v) {
  __hip_atomic_store(p, v, __ATOMIC_RELAXED, __HIP_MEMORY_SCOPE_AGENT);
}
__device__ __forceinline__ void cstorei(int* p, int v) {
  __hip_atomic_store(p, v, __ATOMIC_RELAXED, __HIP_MEMORY_SCOPE_AGENT);
}

// VALU burn while waiting.
__device__ __forceinline__ void fma_burst(float& d0, float& d1, float& d2, float& d3) {
#pragma unroll
  for (int i = 0; i < 16; ++i) {
    d0 = fmaf(d0, 1.0000001f, 1.0f);
    d1 = fmaf(d1, 1.0000002f, 1.0f);
    d2 = fmaf(d2, 1.0000003f, 1.0f);
    d3 = fmaf(d3, 1.0000004f, 1.0f);
  }
}

// Whole-block wait on a PRIVATE mailbox line (value = step t, monotone).
// Wave 0 is the sole memory poller; other waves spin on an LDS release word.
// Bounded: on guard trip we proceed (absmax failure, not a GPU hang).
__device__ __forceinline__ void block_wait(int* mbox, int target, int* lrel, int tok,
                                           int wvid, int lane) {
  float d0 = 0.f, d1 = 0.f, d2 = 0.f, d3 = 0.f;
  int guard = GUARD;
  if (wvid == 0) {
    while (__hip_atomic_load(mbox, __ATOMIC_RELAXED, __HIP_MEMORY_SCOPE_AGENT) < target) {
      fma_burst(d0, d1, d2, d3);
      if (--guard == 0) break;
    }
    __builtin_amdgcn_s_waitcnt(0);
    if (lane == 0)
      __hip_atomic_store(lrel, tok, __ATOMIC_RELAXED, __HIP_MEMORY_SCOPE_WORKGROUP);
  } else {
    while (__hip_atomic_load(lrel, __ATOMIC_RELAXED, __HIP_MEMORY_SCOPE_WORKGROUP) < tok) {
      fma_burst(d0, d1, d2, d3);
      if (--guard == 0) break;
    }
  }
  asm volatile("" :: "v"(d0), "v"(d1), "v"(d2), "v"(d3));
  __syncthreads();
}

struct LayerR {
  const float *saW3, *sab3, *caW0, *cab0, *caW3, *cab3,
              *ffW1, *ffb1, *ffW2, *ffb2, *g0, *be0, *g1, *be1, *g2, *be2;
  float cs1_r, cs2_r, cab1_r, cab2_r;
};

// One wave, one row. K/V in LDS with row stride 65 (bank = (k+e)%32 -> 2-way, free).
__device__ float transformer_row(int lane, int t, float x, float q,
                                 const float* Kb, const float* Vb,
                                 const float* wv, float* xb, float* pb,
                                 const LayerR& P) {
  const float ISQ8 = 0.35355339059327373f;  // 1/sqrt(8)
  // ---- scores: lane = k ----
  xb[lane] = q;
  asm volatile("s_waitcnt lgkmcnt(0)" ::: "memory");
  float a[8] = {0.f, 0.f, 0.f, 0.f, 0.f, 0.f, 0.f, 0.f};
  const float* Krow = Kb + lane * 65;
  const float4* xq4 = (const float4*)xb;
#pragma unroll
  for (int i = 0; i < 16; ++i) {
    float4 xc = xq4[i];
    a[i >> 1] = fmaf(xc.x, Krow[4 * i + 0], a[i >> 1]);
    a[i >> 1] = fmaf(xc.y, Krow[4 * i + 1], a[i >> 1]);
    a[i >> 1] = fmaf(xc.z, Krow[4 * i + 2], a[i >> 1]);
    a[i >> 1] = fmaf(xc.w, Krow[4 * i + 3], a[i >> 1]);
  }
  const bool act = lane < t;
  float m[8];
#pragma unroll
  for (int h = 0; h < 8; ++h) { a[h] = act ? a[h] * ISQ8 : NEG_INF; m[h] = a[h]; }
#pragma unroll
  for (int msk = 1; msk < 64; msk <<= 1) {
#pragma unroll
    for (int h = 0; h < 8; ++h) m[h] = fmaxf(m[h], __shfl_xor(m[h], msk, 64));
  }
  float l[8];
#pragma unroll
  for (int h = 0; h < 8; ++h) { a[h] = act ? expf(a[h] - m[h]) : 0.f; l[h] = a[h]; }
#pragma unroll
  for (int msk = 1; msk < 64; msk <<= 1) {
#pragma unroll
    for (int h = 0; h < 8; ++h) l[h] += __shfl_xor(l[h], msk, 64);
  }
#pragma unroll
  for (int h = 0; h < 8; ++h) pb[h * 64 + lane] = a[h] / l[h];
  asm volatile("s_waitcnt lgkmcnt(0)" ::: "memory");
  // ---- PV: lane = e ----
  const float* pr = pb + (lane >> 3) * 64;
  float attn = 0.f;
  for (int k = 0; k < t; ++k) attn = fmaf(pr[k], Vb[k * 65 + lane], attn);

  float y1 = ln64(x + proj_lds(attn, xb, P.saW3, P.sab3, lane), P.g0, P.be0, lane);
  float qc = proj_lds(y1, xb, P.caW0, P.cab0, lane);
  float pa = red8(qc * P.cs1_r);
  float pc = red8(qc * P.cab1_r);
  const float4* wv4 = (const float4*)wv;
  float mc = NEG_INF;
#pragma unroll
  for (int i = 0; i < 16; ++i) {
    float4 wq = wv4[i];
    int k = 4 * i;
    if (k + 0 < t) mc = fmaxf(mc, fmaf(pa, wq.x, pc));
    if (k + 1 < t) mc = fmaxf(mc, fmaf(pa, wq.y, pc));
    if (k + 2 < t) mc = fmaxf(mc, fmaf(pa, wq.z, pc));
    if (k + 3 < t) mc = fmaxf(mc, fmaf(pa, wq.w, pc));
  }
  float lc = 0.f, z = 0.f;
#pragma unroll
  for (int i = 0; i < 16; ++i) {
    float4 wq = wv4[i];
    int k = 4 * i;
    float wk[4] = {wq.x, wq.y, wq.z, wq.w};
#pragma unroll
    for (int j = 0; j < 4; ++j) {
      if (k + j < t) {
        float raw = fmaf(pa, wk[j], pc);
        float pw = expf((raw - mc) * ISQ8);
        lc += pw;
        z = fmaf(pw, wk[j], z);
      }
    }
  }
  float oc = fmaf(z / lc, P.cs2_r, P.cab2_r);
  float y2 = ln64(y1 + proj_lds(oc, xb, P.caW3, P.cab3, lane), P.g1, P.be1, lane);
  float f = fmaxf(proj_lds(y2, xb, P.ffW1, P.ffb1, lane), 0.f);
  float y3 = ln64(y2 + proj_lds(f, xb, P.ffW2, P.ffb2, lane), P.g2, P.be2, lane);
  return y3;
}

__device__ __forceinline__ void build_layer(LayerR& L, int n, int lane,
    const float* sa_W, const float* sa_b, const float* ca_W, const float* ca_b,
    const float* ff_W1, const float* ff_b1, const float* ff_W2, const float* ff_b2,
    const float* ln_g, const float* ln_b) {
  L.saW3 = sa_W + (n * 4 + 3) * 4096; L.sab3 = sa_b + (n * 4 + 3) * 64;
  L.caW0 = ca_W + (n * 4 + 0) * 4096; L.cab0 = ca_b + (n * 4 + 0) * 64;
  L.caW3 = ca_W + (n * 4 + 3) * 4096; L.cab3 = ca_b + (n * 4 + 3) * 64;
  L.ffW1 = ff_W1 + n * 4096;          L.ffb1 = ff_b1 + n * 64;
  L.ffW2 = ff_W2 + n * 4096;          L.ffb2 = ff_b2 + n * 64;
  L.g0 = ln_g + (n * 3 + 0) * 64;     L.be0 = ln_b + (n * 3 + 0) * 64;
  L.g1 = ln_g + (n * 3 + 1) * 64;     L.be1 = ln_b + (n * 3 + 1) * 64;
  L.g2 = ln_g + (n * 3 + 2) * 64;     L.be2 = ln_b + (n * 3 + 2) * 64;
  L.cab1_r = ca_b[(n * 4 + 1) * 64 + lane];
  L.cab2_r = ca_b[(n * 4 + 2) * 64 + lane];
  float c1 = 0.f, c2 = 0.f;
  for (int e = 0; e < 64; ++e) {
    c1 += ca_W[(n * 4 + 1) * 4096 + e * 64 + lane];
    c2 += ca_W[(n * 4 + 2) * 4096 + e * 64 + lane];
  }
  L.cs1_r = c1; L.cs2_r = c2;
}

__global__ __launch_bounds__(1024) void gen_kernel(
    const float* __restrict__ noise, const float* __restrict__ lin_W,
    const float* __restrict__ lin_b, const float* __restrict__ sa_W,
    const float* __restrict__ sa_b, const float* __restrict__ ca_W,
    const float* __restrict__ ca_b, const float* __restrict__ ff_W1,
    const float* __restrict__ ff_b1, const float* __restrict__ ff_W2,
    const float* __restrict__ ff_b2, const float* __restrict__ ln_g,
    const float* __restrict__ ln_b, const float* __restrict__ emb,
    const float* __restrict__ soft_W, const float* __restrict__ soft_b,
    const int* __restrict__ start_id, float* __restrict__ dout,
    float* __restrict__ wsf) {
  const int tid = threadIdx.x, lane = tid & 63, wvid = tid >> 6;
  const int bid = blockIdx.x;

  // ---- workspace: counters + private mailboxes in first 64 KB (memset-zeroed) ----
  int* wsi = (int*)wsf;
  int* Ff  = wsi;          // [64]  tok_feat arrivals (target NB; detector fans out)
  int* C3f = wsi + 64;     // [64]  vocab-stats arrivals (target NVB; last reduces+fans)
  int* Af  = wsi + 128;    // [8][64] layer-1 arrivals (target 4; detector fans to tail)
  int* mbA = wsi + 1024;   // [32][32]  per-batch-block mailbox (Af complete), 128B stride
  int* mbF = wsi + 2048;   // [127][32] per-vocab-block mailbox (tok_feat ready)
  int* mbR = wsi + 8192;   // [159][32] per-block mailbox (reduce ready)
  float* tokf_g  = wsf + 16384;          // (8,64)
  float* stats_m = wsf + 16896;          // (8,128) use NVB
  float* stats_s = wsf + 17920;          // (8,128)
  int*   stats_i = (int*)(wsf + 18944);  // (8,128)
  float* mS_g    = wsf + 19968;          // (8,2)
  int*   ig_g    = (int*)(wsf + 20032);  // (8)
  float* K2g = wsf + 24576;              // (8,64,64)
  float* V2g = K2g + 32768;

  __shared__ float lds[26368];          // 105472 B

  if (bid < NBB) {
    // ========== batch sub-block: 1 of 4 per batch, 16 rows, 1 row/wave ==========
    const int b = bid >> 2, sb = bid & 3;
    const int myrow = sb * 16 + wvid;   // row owned by this wave
    float* K1  = lds;                   // 63 rows, stride 65 (local mirror, locally built)
    float* V1  = lds + 4096;
    float* K2  = lds + 8192;            // tail block only
    float* V2  = lds + 12288;
    float* wvl = lds + 16384;           // (64)
    float* x2s = lds + 16448;           // (64) layer-1 out of row t-1
    float* ynew = lds + 16512;          // (64) new row broadcast
    float* xbuf = lds + 16576;          // 16 waves * 64
    float* pbuf = lds + 17600;          // 16 waves * 512
    int* lrelA = (int*)(lds + 25792);   // LDS release counters for block_wait
    int* lrelR = (int*)(lds + 25793);
    float* myxb = xbuf + wvid * 64;
    float* mypb = pbuf + wvid * 512;

    LayerR L0, L1;
    build_layer(L0, 0, lane, sa_W, sa_b, ca_W, ca_b, ff_W1, ff_b1, ff_W2, ff_b2, ln_g, ln_b);
    build_layer(L1, 1, lane, sa_W, sa_b, ca_W, ca_b, ff_W1, ff_b1, ff_W2, ff_b2, ln_g, ln_b);

    float x_r = 0.f, q_r = 0.f;
    if (tid == 0) { *lrelA = 0; *lrelR = 0; }

    if (wvid == 0) {
      // every sub-block computes wvl + seed row locally (no cross-block handoff)
      float nz = noise[b * 64 + lane];
      float t1v = proj_lds(nz, myxb, lin_W, lin_b, lane);
      wvl[lane] = proj_lds(t1v, myxb, lin_W + 4096, lin_b + 64, lane);
      float y0 = emb[start_id[0] * 64 + lane] + ((lane & 1) ? 1.0f : 0.0f);
      float k0 = proj_lds(y0, myxb, sa_W + 4096, sa_b + 64, lane);
      float v0 = proj_lds(y0, myxb, sa_W + 2 * 4096, sa_b + 128, lane);
      K1[lane] = k0; V1[lane] = v0;
      if (sb == 0) {  // owner of row 0
        x_r = y0;
        q_r = proj_lds(y0, myxb, sa_W, sa_b, lane);
      }
    }
    __syncthreads();

    for (int t = 1; t <= 63; ++t) {
      const int tailsb = (t - 1) >> 4;
      const bool istail = (sb == tailsb);
      // ---- layer-1: one row per wave, all rows in parallel ----
      if (myrow < t) {
        float out = transformer_row(lane, t, x_r, q_r, K1, V1, wvl, myxb, mypb, L0);
        float k2 = proj_lds(out, myxb, sa_W + 5 * 4096, sa_b + 5 * 64, lane);
        float v2 = proj_lds(out, myxb, sa_W + 6 * 4096, sa_b + 6 * 64, lane);
        cstoref(K2g + b * 4096 + myrow * 64 + lane, k2);
        cstoref(V2g + b * 4096 + myrow * 64 + lane, v2);
        if (istail) { K2[myrow * 65 + lane] = k2; V2[myrow * 65 + lane] = v2; }
        if (myrow == t - 1) x2s[lane] = out;
        __builtin_amdgcn_s_waitcnt(0);  // drain my agent stores before counting in
      }
      __syncthreads();
      if (tid == 0) {
        int old = __hip_atomic_fetch_add(&Af[b * 64 + t], 1,
                                         __ATOMIC_RELAXED, __HIP_MEMORY_SCOPE_AGENT);
        if (old == 3)  // detector: wake this batch's tail block via its private line
          cstorei(mbA + (b * 4 + tailsb) * 32, t);
      }

      if (istail) {
        // ---- gather non-own K2/V2 rows (parallel across waves), layer-2 on wave 0 ----
        block_wait(mbA + bid * 32, t, lrelA, t, wvid, lane);
        const int lo = sb * 16, hi = lo + 16;
        for (int r = wvid; r < t; r += 16) {
          if (r < lo || r >= hi) {
            K2[r * 65 + lane] = cloadf(K2g + b * 4096 + r * 64 + lane);
            V2[r * 65 + lane] = cloadf(V2g + b * 4096 + r * 64 + lane);
          }
        }
        __syncthreads();
        if (wvid == 0) {
          float x2 = x2s[lane];
          float q2 = proj_lds(x2, myxb, sa_W + 4 * 4096, sa_b + 4 * 64, lane);
          float tf = transformer_row(lane, t, x2, q2, K2, V2, wvl, myxb, mypb, L1);
          cstoref(tokf_g + b * 64 + lane, tf);
          __builtin_amdgcn_s_waitcnt(0);
          int old = 0;
          if (lane == 0)
            old = __hip_atomic_fetch_add(&Ff[t], 1,
                                         __ATOMIC_RELAXED, __HIP_MEMORY_SCOPE_AGENT);
          old = __shfl(old, 0, 64);
          if (old == NB - 1) {  // detector: fan out to all 127 vocab mailboxes
            for (int i = lane; i < NVB; i += 64) cstorei(mbF + i * 32, t);
          }
        }
      }

      // ---- new-row phase: every sub-block rebuilds row t locally after argmax ----
      if (t < 63) {
        float pev = 0.f;
        if (wvid == 0) {  // pe[t] — argmax-independent, overlaps the wait below
          double ang = (double)t / pow(10000.0, (double)(lane & 62) / 64.0);
          pev = (lane & 1) ? (float)cos(ang) : (float)sin(ang);
        }
        block_wait(mbR + bid * 32, t, lrelR, t, wvid, lane);
        if (wvid == 0) {
          int ig = cloadi(&ig_g[b]);
          float y = emb[ig * 64 + lane] + pev;
          float kn = proj_lds(y, myxb, sa_W + 4096, sa_b + 64, lane);
          float vn = proj_lds(y, myxb, sa_W + 2 * 4096, sa_b + 128, lane);
          K1[t * 65 + lane] = kn;
          V1[t * 65 + lane] = vn;
          ynew[lane] = y;
        }
        __syncthreads();
        if (sb == (t >> 4) && wvid == (t & 15)) {  // owner wave of row t
          x_r = ynew[lane];
          q_r = proj_lds(x_r, myxb, sa_W, sa_b, lane);
        }
      }
    }
  } else {
    // =================== vocab block: LDS-resident 397-column slice ===================
    const int jb = bid - NBB;
    const int v = jb * VCOLS + tid;
    const bool valid = (tid < VCOLS) && (v < Vc);
    float* sW  = lds;                   // (64, 397) LDS-resident soft_W slice
    float* f2  = lds + 25408;           // (64,8) ftile transposed, e*8+b
    float* sm  = lds + 25920;           // (16,8)
    int*   si  = (int*)(lds + 26048);
    float* ssm = lds + 26176;           // (16,8)
    float* bmx = lds + 26304;           // (8)
    int*   bix = (int*)(lds + 26312);
    float* msl = lds + 26320;           // (16)
    int*   red = (int*)(lds + 26336);
    int* lrelF = (int*)(lds + 26344);
    int* lrelR2 = (int*)(lds + 26345);
    float sb = valid ? soft_b[v] : 0.f;

    if (tid == 0) { *lrelF = 0; *lrelR2 = 0; }
    // one-time stage of this block's soft_W slice into LDS (~102 KB)
    if (tid < VCOLS) {
      for (int e = 0; e < 64; ++e)
        sW[e * VCOLS + tid] = (v < Vc) ? soft_W[e * Vc + v] : 0.f;
    }
    __syncthreads();

    for (int t = 1; t <= 63; ++t) {
      block_wait(mbF + jb * 32, t, lrelF, t, wvid, lane);
      // rotated pull order per block de-serializes the shared tokf_g read burst
      if (tid < 512) {
        int u = (tid + jb * 37) & 511;
        f2[u] = cloadf(&tokf_g[(u & 7) * 64 + (u >> 3)]);
      }
      __syncthreads();
      float lg[8];
#pragma unroll
      for (int b = 0; b < 8; ++b) lg[b] = valid ? sb : NEG_INF;
      if (valid) {
        const float4* f4 = (const float4*)f2;
        const float* col = sW + tid;
#pragma unroll 8
        for (int e = 0; e < 64; ++e) {
          float wc = col[e * VCOLS];
          float4 fa = f4[2 * e], fb = f4[2 * e + 1];
          lg[0] = fmaf(fa.x, wc, lg[0]);
          lg[1] = fmaf(fa.y, wc, lg[1]);
          lg[2] = fmaf(fa.z, wc, lg[2]);
          lg[3] = fmaf(fa.w, wc, lg[3]);
          lg[4] = fmaf(fb.x, wc, lg[4]);
          lg[5] = fmaf(fb.y, wc, lg[5]);
          lg[6] = fmaf(fb.z, wc, lg[6]);
          lg[7] = fmaf(fb.w, wc, lg[7]);
        }
      }
#pragma unroll
      for (int b = 0; b < 8; ++b) {
        float m = lg[b]; int ix = valid ? v : 0x7fffffff;
#pragma unroll
        for (int msk = 1; msk < 64; msk <<= 1) {
          float om = __shfl_xor(m, msk, 64);
          int oi = __shfl_xor(ix, msk, 64);
          if (om > m || (om == m && oi < ix)) { m = om; ix = oi; }
        }
        if (lane == 0) { sm[wvid * 8 + b] = m; si[wvid * 8 + b] = ix; }
      }
      __syncthreads();
      if (tid < 8) {
        float m = NEG_INF; int ix = 0x7fffffff;
        for (int wv = 0; wv < 16; ++wv) {
          float om = sm[wv * 8 + tid]; int oi = si[wv * 8 + tid];
          if (om > m || (om == m && oi < ix)) { m = om; ix = oi; }
        }
        bmx[tid] = m; bix[tid] = ix;
      }
      __syncthreads();
#pragma unroll
      for (int b = 0; b < 8; ++b) {
        float c = valid ? expf(lg[b] - bmx[b]) : 0.f;
        float s = wsum64(c);
        if (lane == 0) ssm[wvid * 8 + b] = s;
      }
      __syncthreads();
      if (wvid == 0) {
        if (lane < 8) {
          float s = 0.f;
          for (int wv = 0; wv < 16; ++wv) s += ssm[wv * 8 + lane];
          cstoref(&stats_m[lane * 128 + jb], bmx[lane]);
          cstoref(&stats_s[lane * 128 + jb], s);
          cstorei(&stats_i[lane * 128 + jb], bix[lane]);
        }
        __builtin_amdgcn_s_waitcnt(0);  // stats at coherence point before counting in
        if (lane == 0)
          red[0] = __hip_atomic_fetch_add(&C3f[t], 1,
                                          __ATOMIC_RELAXED, __HIP_MEMORY_SCOPE_AGENT);
      }
      __syncthreads();
      if (red[0] == NVB - 1) {
        // last-arriving vocab block reduces all 8 batches, then fans out mbR
        if (wvid < 8) {
          const int b2 = wvid;
          float mA = cloadf(&stats_m[b2 * 128 + lane]);
          float sA = cloadf(&stats_s[b2 * 128 + lane]);
          int   iA = cloadi(&stats_i[b2 * 128 + lane]);
          const bool a2 = lane < (NVB - 64);
          float mB = a2 ? cloadf(&stats_m[b2 * 128 + 64 + lane]) : NEG_INF;
          float sB = a2 ? cloadf(&stats_s[b2 * 128 + 64 + lane]) : 0.f;
          int   iB = a2 ? cloadi(&stats_i[b2 * 128 + 64 + lane]) : 0x7fffffff;
          float mg = mA; int ig = iA;
          if (mB > mg || (mB == mg && iB < ig)) { mg = mB; ig = iB; }
#pragma unroll
          for (int msk = 1; msk < 64; msk <<= 1) {
            float om = __shfl_xor(mg, msk, 64);
            int oi = __shfl_xor(ig, msk, 64);
            if (om > mg || (om == mg && oi < ig)) { mg = om; ig = oi; }
          }
          float part = sA * expf(mA - mg) + (a2 ? sB * expf(mB - mg) : 0.f);
          float S = wsum64(part);
          if (lane == 0) {
            cstoref(&mS_g[b2 * 2], mg);
            cstoref(&mS_g[b2 * 2 + 1], S);
            cstorei(&ig_g[b2], ig);
          }
          __builtin_amdgcn_s_waitcnt(0);  // each reducing wave drains its own stores
        }
        __syncthreads();
        if (tid < NBB + NVB) cstorei(mbR + tid * 32, t);  // private-line fan-out
      }
      block_wait(mbR + (NBB + jb) * 32, t, lrelR2, t, wvid, lane);
      if (tid < 16) msl[tid] = cloadf(&mS_g[tid]);
      __syncthreads();
      if (valid) {
        long base = (long)(t - 1) * Vc + v;
#pragma unroll
        for (int b = 0; b < 8; ++b)
          dout[(long)b * 63 * Vc + base] = expf(lg[b] - msl[2 * b]) / msl[2 * b + 1];
      }
      __syncthreads();
    }
  }
}

extern "C" void kernel_launch(void* const* d_in, const int* in_sizes, int n_in,
                              void* d_out, int out_size, void* d_ws, size_t ws_size,
                              hipStream_t stream) {
  (void)in_sizes; (void)n_in; (void)out_size; (void)ws_size;
  hipMemsetAsync(d_ws, 0, 65536, stream);  // zero counters + mailboxes
  gen_kernel<<<dim3(NBB + NVB), dim3(1024), 0, stream>>>(
      (const float*)d_in[0], (const float*)d_in[1], (const float*)d_in[2],
      (const float*)d_in[3], (const float*)d_in[4], (const float*)d_in[5],
      (const float*)d_in[6], (const float*)d_in[7], (const float*)d_in[8],
      (const float*)d_in[9], (const float*)d_in[10], (const float*)d_in[11],
      (const float*)d_in[12], (const float*)d_in[13], (const float*)d_in[14],
      (const float*)d_in[15], (const int*)d_in[16],
      (float*)d_out, (float*)d_ws);
}